// Round 11
// baseline (1393.576 us; speedup 1.0000x reference)
//
#include <hip/hip_runtime.h>
#include <math.h>

#define NXQ 729
#define M2Q 128
#define MQ  857
#define BQ  16
#define QPEN_ 0.1
#define SIGMA_ 0.1

typedef double d4 __attribute__((ext_vector_type(4)));

// workspace offsets (in doubles)
constexpr int OFF_P    = 0;                        // 16x729
constexpr int OFF_H2   = OFF_P + BQ*NXQ;           // 128
constexpr int OFF_Z    = OFF_H2 + M2Q;             // 16x729
constexpr int OFF_S    = OFF_Z + BQ*NXQ;           // 16x857
constexpr int OFF_LAM  = OFF_S + BQ*MQ;            // 16x857
constexpr int OFF_D    = OFF_LAM + BQ*MQ;          // 16x857
constexpr int OFF_RP   = OFF_D + BQ*MQ;            // 16x857
constexpr int OFF_V    = OFF_RP + BQ*MQ;           // 16x857
constexpr int OFF_AINV = OFF_V + BQ*MQ;            // 16x729
constexpr int OFF_Y    = OFF_AINV + BQ*NXQ;        // 16x729
constexpr int OFF_GZ2  = OFF_Y + BQ*NXQ;           // 16x128
constexpr int OFF_Q2   = OFF_GZ2 + BQ*M2Q;         // 16x128
constexpr int OFF_USOL = OFF_Q2 + BQ*M2Q;          // 16x128
constexpr int OFF_G2B  = OFF_USOL + BQ*M2Q;        // 16x128
constexpr int OFF_TP   = OFF_G2B + BQ*M2Q;         // 12x16x128 t partials
constexpr int OFF_CMIN = OFF_TP + 12*BQ*M2Q;       // 13x16 alpha partial mins
constexpr int OFF_SG   = OFF_CMIN + 13*BQ + 48;    // 16x128x128 S matrices
constexpr int OFF_DZS  = OFF_SG;                   // 16x768 ALIASES SG prefix
constexpr int OFF_CNTD = OFF_SG + BQ*M2Q*M2Q;      // dz->upd counters (16 uints)

// solve LDS layout (doubles)
constexpr int L_SL   = 0;                  // 128 x 129 = 16512
constexpr int L_US   = 16512;              // 128
constexpr int L_INVD = 16640;              // 128
constexpr int L_RED  = 16768;              // 8
constexpr int L_LI   = 16776;              // 16 x 17 = 272 (invL11)
constexpr int SH_SOLVE = (L_LI + 272) * 8; // 136384 B -> 1 block/CU
constexpr int SH_PS    = 4 * 2176 * 8;     // 69632 B

__device__ __forceinline__ double wred_sum(double v) {
#pragma unroll
  for (int off = 32; off > 0; off >>= 1) v += __shfl_down(v, off, 64);
  return v;
}
__device__ __forceinline__ double wred_min(double v) {
#pragma unroll
  for (int off = 32; off > 0; off >>= 1) v = fmin(v, __shfl_down(v, off, 64));
  return v;
}
// f32-seeded fp64 rsqrt: seed err ~1e-7 -> 2 Newton -> ~1 ulp.
__device__ __forceinline__ double rsqrt64(double x) {
  double r = (double)rsqrtf((float)x);
  r = r * (1.5 - 0.5 * x * r * r);
  r = r * (1.5 - 0.5 * x * r * r);
  return r;
}

// ---------------------------------------------------------------------------
// init: grid 144 x 512 (R9 verbatim)
// ---------------------------------------------------------------------------
__global__ __launch_bounds__(512)
void init_kernel(const float* __restrict__ puzzles, const float* __restrict__ G2,
                 const float* __restrict__ z2in, const float* __restrict__ s2in,
                 double* __restrict__ ws) {
  const int blk = blockIdx.x;
  const int tid = threadIdx.x, wave = tid >> 6, lane = tid & 63;
  __shared__ double sm[32];
  if (blk < BQ) {
    const int bb = blk;
    for (int i = tid; i < NXQ; i += 512) {
      ws[OFF_P + bb * NXQ + i] = -(double)puzzles[bb * NXQ + i];
      ws[OFF_Z + bb * NXQ + i] = 0.0;
      ws[OFF_AINV + bb * NXQ + i] = 1.0 / (QPEN_ + 1.0);
      ws[OFF_RP + bb * MQ + i] = 1.0;
      ws[OFF_V + bb * MQ + i] = SIGMA_;
    }
    for (int i = tid; i < MQ; i += 512) {
      ws[OFF_S + bb * MQ + i] = 1.0;
      ws[OFF_LAM + bb * MQ + i] = 1.0;
      ws[OFF_D + bb * MQ + i] = 1.0;
    }
    if (tid < M2Q) ws[OFF_GZ2 + bb * M2Q + tid] = 0.0;
    if (tid == 0) ((unsigned*)(ws + OFF_CNTD))[bb] = 0u;
  } else {
    const int r = blk - 16;
    double acc = 0.0;
    for (int kx = tid; kx < NXQ; kx += 512)
      acc += (double)G2[r * NXQ + kx] * (double)z2in[kx];
    acc = wred_sum(acc);
    if (lane == 0) sm[wave] = acc;
    __syncthreads();
    if (tid == 0) {
      double t = 0.0;
#pragma unroll
      for (int w = 0; w < 8; ++w) t += sm[w];
      const double h2r = t + (double)s2in[r];
      ws[OFF_H2 + r] = h2r;
      sm[16] = h2r;
    }
    __syncthreads();
    if (tid < BQ) {
      const double rp2 = 1.0 - sm[16];
      ws[OFF_RP + tid * MQ + NXQ + r] = rp2;
      ws[OFF_V  + tid * MQ + NXQ + r] = rp2 - 0.9;
      ws[OFF_Q2 + tid * M2Q + r] = rp2 + 0.1;
    }
  }
}

// ---------------------------------------------------------------------------
// ps: grid (16 tiles, 16 batches) x 512 (R9 verbatim)
// ---------------------------------------------------------------------------
__global__ __launch_bounds__(512)
void ps_kernel(const float* __restrict__ G2, double* __restrict__ ws) {
  const int tile = blockIdx.x, b = blockIdx.y;
  const int tid = threadIdx.x, wave = tid >> 6, lane = tid & 63;
  extern __shared__ double sm[];

  if (tile < 12) {
    double* uvec = sm;
    double* part = sm + 128;
    double* yl   = sm + 640;
    const int c0 = tile * 64;
    if (tid < M2Q) uvec[tid] = ws[OFF_Q2 + b * M2Q + tid];
    __syncthreads();
    const int kk = tid & 63, rq = tid >> 6;
    const int k = c0 + kk;
    const int kg = (k < NXQ) ? k : (NXQ - 1);
    {
      const float* gp = G2 + (rq * 16) * NXQ + kg;
      double acc = 0.0;
#pragma unroll
      for (int j = 0; j < 16; ++j) acc = fma((double)gp[j * NXQ], uvec[rq * 16 + j], acc);
      part[rq * 64 + kk] = acc;
    }
    __syncthreads();
    if (tid < 64) {
      const int k2 = c0 + tid;
      double y = 0.0;
      if (k2 < NXQ) {
        double w = 0.0;
#pragma unroll
        for (int q = 0; q < 8; ++q) w += part[q * 64 + tid];
        const double rhsk = -(QPEN_ * ws[OFF_Z + b * NXQ + k2] + ws[OFF_P + b * NXQ + k2]
                              - ws[OFF_LAM + b * MQ + k2] - ws[OFF_V + b * MQ + k2] + w);
        y = ws[OFF_AINV + b * NXQ + k2] * rhsk;
        ws[OFF_Y + b * NXQ + k2] = y;
      }
      yl[tid] = y;
    }
    __syncthreads();
    const double yv = yl[lane];
#pragma unroll
    for (int jr = 0; jr < 16; ++jr) {
      const int r = (tid >> 6) * 16 + jr;
      double v = (double)G2[r * NXQ + kg] * yv;
      v = wred_sum(v);
      if (lane == 0) ws[OFF_TP + (tile * BQ + b) * M2Q + r] = v;
    }
    __syncthreads();
  }

  const int R0 = (tile >> 2) * 32, C0 = (tile & 3) * 32;
  double* As = sm + wave * 2176;
  double* Bs = As + 1088;
  const double* __restrict__ ainv = ws + OFF_AINV + b * NXQ;
  const int k0w = wave * 183;
  const int kend = min(k0w + 183, NXQ);
  const int rg4 = (lane >> 3) * 4, cg4 = (lane & 7) * 4;
  double acc[4][4];
#pragma unroll
  for (int i = 0; i < 4; ++i)
#pragma unroll
    for (int j = 0; j < 4; ++j) acc[i][j] = 0.0;

  const int kk2 = lane & 31;
  for (int ch = 0; ch < 6; ++ch) {
    __syncthreads();
    if (wave < 4) {
      const int k = k0w + ch * 32 + kk2;
      const bool ok = (k < kend);
      const double aik = ok ? ainv[k] : 0.0;
#pragma unroll
      for (int it = 0; it < 16; ++it) {
        const int rr = (it << 1) | (lane >> 5);
        double av = 0.0, bv = 0.0;
        if (ok) {
          av = (double)G2[(R0 + rr) * NXQ + k] * aik;
          bv = (double)G2[(C0 + rr) * NXQ + k];
        }
        As[kk2 * 34 + rr] = av;
        Bs[kk2 * 34 + rr] = bv;
      }
    }
    __syncthreads();
    if (wave < 4) {
#pragma unroll 8
      for (int q = 0; q < 32; ++q) {
        const double a0 = As[q*34 + rg4 + 0], a1 = As[q*34 + rg4 + 1],
                     a2 = As[q*34 + rg4 + 2], a3 = As[q*34 + rg4 + 3];
        const double b0 = Bs[q*34 + cg4 + 0], b1 = Bs[q*34 + cg4 + 1],
                     b2 = Bs[q*34 + cg4 + 2], b3 = Bs[q*34 + cg4 + 3];
        acc[0][0] += a0*b0; acc[0][1] += a0*b1; acc[0][2] += a0*b2; acc[0][3] += a0*b3;
        acc[1][0] += a1*b0; acc[1][1] += a1*b1; acc[1][2] += a1*b2; acc[1][3] += a1*b3;
        acc[2][0] += a2*b0; acc[2][1] += a2*b1; acc[2][2] += a2*b2; acc[2][3] += a2*b3;
        acc[3][0] += a3*b0; acc[3][1] += a3*b1; acc[3][2] += a3*b2; acc[3][3] += a3*b3;
      }
    }
  }
  __syncthreads();
  if (wave < 4) {
#pragma unroll
    for (int i = 0; i < 4; ++i)
#pragma unroll
      for (int j = 0; j < 4; ++j)
        As[(rg4 + i) * 32 + cg4 + j] = acc[i][j];
  }
  __syncthreads();
  double* __restrict__ Sgb = ws + OFF_SG + b * (M2Q * M2Q);
  for (int idx = tid; idx < 1024; idx += 512) {
    const double v = sm[idx] + sm[2176 + idx] + sm[4352 + idx] + sm[6528 + idx];
    Sgb[(R0 + (idx >> 5)) * M2Q + C0 + (idx & 31)] = v;
  }
}

// ---------------------------------------------------------------------------
// solve: 16 blocks x 512. Cholesky with MFMA TRSM via explicit invL11.
// ---------------------------------------------------------------------------
__global__ __launch_bounds__(512, 1)
void solve_kernel(double* __restrict__ ws) {
  const int b = blockIdx.x;
  const int tid = threadIdx.x, wave = tid >> 6, lane = tid & 63;
  extern __shared__ double sm[];
  double (*Sl)[129] = (double(*)[129])(sm + L_SL);
  double* us   = sm + L_US;
  double* invd = sm + L_INVD;
  double* red  = sm + L_RED;
  double* Li   = sm + L_LI;    // 16 x 17
  double* s_   = ws + OFF_S   + b * MQ;
  double* lam_ = ws + OFF_LAM + b * MQ;
  double* Sgb  = ws + OFF_SG  + b * M2Q * M2Q;

  {
    const double2* __restrict__ Sg2 = (const double2*)Sgb;
    for (int idx = tid; idx < M2Q * M2Q / 2; idx += 512) {
      const double2 v = Sg2[idx];
      const int r = idx >> 6, c = (idx & 63) * 2;
      Sl[r][c] = v.x; Sl[r][c + 1] = v.y;
    }
  }
  if (tid < M2Q) {
    double t = 0.0;
#pragma unroll
    for (int c = 0; c < 12; ++c) t += ws[OFF_TP + (c * BQ + b) * M2Q + tid];
    us[tid] = t;
  }
  __syncthreads();
  if (tid < M2Q) Sl[tid][tid] += s_[NXQ + tid] / lam_[NXQ + tid];
  __syncthreads();

  // runtime probe of f64 MFMA C/D register->(row,col) mapping (verified R4)
  int rowm[4], colm[4];
  {
    const int rc = lane & 15, kq = lane >> 4;
    const double avr = (kq == 0) ? (double)rc : 0.0;
    const double bv1 = (kq == 0) ? 1.0 : 0.0;
    const double av1 = (kq == 0) ? 1.0 : 0.0;
    const double bvc = (kq == 0) ? (double)rc : 0.0;
    d4 zero = {0.0, 0.0, 0.0, 0.0};
    d4 dr = __builtin_amdgcn_mfma_f64_16x16x4f64(avr, bv1, zero, 0, 0, 0);
    d4 dc = __builtin_amdgcn_mfma_f64_16x16x4f64(av1, bvc, zero, 0, 0, 0);
#pragma unroll
    for (int e = 0; e < 4; ++e) { rowm[e] = (int)dr[e]; colm[e] = (int)dc[e]; }
  }

  // blocked Cholesky (NB=16): wave0 {micro-chol + invL11 + u1}; MFMA TRSM; SYRK
  for (int kb = 0; kb < 8; ++kb) {
    const int K0 = kb * 16, J0 = K0 + 16, T = 128 - J0;
    if (wave == 0 && lane < 16) {
      const int r = lane;
      // micro-Cholesky (lane = row)
      double a[16];
#pragma unroll
      for (int c = 0; c < 16; ++c) a[c] = Sl[K0 + r][K0 + c];
#pragma unroll
      for (int c = 0; c < 16; ++c) {
        const double dcc = __shfl(a[c], c, 64);
        const double rs = rsqrt64(dcc);
        a[c] *= rs;
        if (lane == c) invd[K0 + c] = rs;
#pragma unroll
        for (int k2 = c + 1; k2 < 16; ++k2) {
          const double lkc = __shfl(a[c], k2, 64);
          a[k2] = fma(-a[c], lkc, a[k2]);
        }
      }
#pragma unroll
      for (int c = 0; c < 16; ++c) Sl[K0 + r][K0 + c] = a[c];
      // invL11 column j = lane: solve L11 x = e_j (x[m<j] = 0)
      const int j = lane;
      double x[16];
#pragma unroll
      for (int rr = 0; rr < 16; ++rr) x[rr] = 0.0;
#pragma unroll
      for (int rr = 0; rr < 16; ++rr) {
        if (rr >= j) {
          double acc = (rr == j) ? 1.0 : 0.0;
#pragma unroll
          for (int m = 0; m < 16; ++m)
            if (m < rr) acc = fma(-Sl[K0 + rr][K0 + m], x[m], acc);
          x[rr] = acc * invd[K0 + rr];
        }
      }
#pragma unroll
      for (int rr = 0; rr < 16; ++rr) Li[rr * 17 + j] = x[rr];
      // u1 = invL11 * u1 (row-dot per lane; same-wave LDS ordering is safe)
      double un = 0.0;
#pragma unroll
      for (int jj = 0; jj < 16; ++jj) un = fma(Li[r * 17 + jj], us[K0 + jj], un);
      us[K0 + r] = un;
    }
    __syncthreads();

    if (kb < 7) {
      // TRSM via MFMA: L21 = A21 * invL11^T (same A/B convention as SYRK)
      const int Tb = 7 - kb;
      const int rc = lane & 15, kq = lane >> 4;
      double bfrag[4];
#pragma unroll
      for (int m = 0; m < 4; ++m) bfrag[m] = Li[rc * 17 + 4 * m + kq];
      for (int idx = wave; idx < Tb; idx += 8) {
        const int i0 = J0 + idx * 16;
        d4 acc = {0.0, 0.0, 0.0, 0.0};
#pragma unroll
        for (int m = 0; m < 4; ++m) {
          const double av = Sl[i0 + rc][K0 + 4 * m + kq];
          acc = __builtin_amdgcn_mfma_f64_16x16x4f64(av, bfrag[m], acc, 0, 0, 0);
        }
#pragma unroll
        for (int e = 0; e < 4; ++e) Sl[i0 + rowm[e]][K0 + colm[e]] = acc[e];
      }
      __syncthreads();
      // u2 -= L21 * u1
      if (tid < T) {
        double acc = 0.0;
#pragma unroll
        for (int c = 0; c < 16; ++c) acc = fma(Sl[J0 + tid][K0 + c], us[K0 + c], acc);
        us[J0 + tid] -= acc;
      }
      // SYRK via MFMA: A22 -= L21 * L21^T (full-square tiles)
      {
        const int rc2 = lane & 15, kq2 = lane >> 4;
        for (int idx = wave; idx < Tb * Tb; idx += 8) {
          const int i0 = J0 + (idx / Tb) * 16;
          const int j0 = J0 + (idx % Tb) * 16;
          d4 acc;
#pragma unroll
          for (int e = 0; e < 4; ++e) acc[e] = Sl[i0 + rowm[e]][j0 + colm[e]];
#pragma unroll
          for (int m = 0; m < 4; ++m) {
            const double av = -Sl[i0 + rc2][K0 + 4 * m + kq2];
            const double bv =  Sl[j0 + rc2][K0 + 4 * m + kq2];
            acc = __builtin_amdgcn_mfma_f64_16x16x4f64(av, bv, acc, 0, 0, 0);
          }
#pragma unroll
          for (int e = 0; e < 4; ++e) Sl[i0 + rowm[e]][j0 + colm[e]] = acc[e];
        }
      }
    }
    __syncthreads();
  }

  // backward substitution L^T u = u'
  for (int kb = 7; kb >= 0; --kb) {
    const int K0 = kb * 16;
    if (kb < 7) {
      // one column per 32-lane half-wave
      const int col = tid >> 5, hl = tid & 31;
      double part = 0.0;
      for (int k = K0 + 16 + hl; k < 128; k += 32) part = fma(Sl[k][K0 + col], us[k], part);
#pragma unroll
      for (int off = 16; off > 0; off >>= 1) part += __shfl_down(part, off, 64);
      if (hl == 0) us[K0 + col] -= part;
      __syncthreads();
    }
    if (wave == 0 && lane < 16) {
      const int j = lane;
      double colv[16];
#pragma unroll
      for (int c = 0; c < 16; ++c) colv[c] = Sl[K0 + c][K0 + j];
      double x = us[K0 + j];
      const double iv = invd[K0 + j];
#pragma unroll
      for (int cc = 0; cc < 16; ++cc) {
        const int c = 15 - cc;
        const double xiv = x * iv;
        const double uc = __shfl(xiv, c, 64);
        if (j == c) x = xiv;
        else if (j < c) x = fma(-colv[c], uc, x);
      }
      us[K0 + j] = x;
    }
    __syncthreads();
  }

  // tail: write u, g2b = D2inv*u; m2-part ratio min -> cmin slot 12
  double lmin = 1e300;
  if (tid < M2Q) {
    const double u = us[tid];
    ws[OFF_USOL + b * M2Q + tid] = u;
    const double g = (s_[NXQ + tid] / lam_[NXQ + tid]) * u;
    ws[OFF_G2B + b * M2Q + tid] = g;
    const int i = NXQ + tid;
    const double dsi = -ws[OFF_RP + b * MQ + i] - g;
    const double dlami = ws[OFF_V + b * MQ + i] + ws[OFF_D + b * MQ + i] * g;
    if (dsi < 0.0)   lmin = fmin(lmin, -s_[i] / dsi);
    if (dlami < 0.0) lmin = fmin(lmin, -lam_[i] / dlami);
  }
  if (tid < 128) {
    lmin = wred_min(lmin);
    if (lane == 0) red[wave] = lmin;
  }
  __syncthreads();
  if (tid == 0) ws[OFF_CMIN + 12 * BQ + b] = fmin(red[0], red[1]);
}

// ---------------------------------------------------------------------------
// dzupd: grid (12 chunks, 16 batches) x 512 (R9 verbatim)
// ---------------------------------------------------------------------------
__global__ __launch_bounds__(512)
void dzupd_kernel(const float* __restrict__ G2, double* __restrict__ ws,
                  float* __restrict__ out, const int last) {
  const int chunk = blockIdx.x, b = blockIdx.y;
  const int tid = threadIdx.x, lane = tid & 63, wave = tid >> 6;
  __shared__ double uvec[128];
  __shared__ double part[512];
  __shared__ double red[8];
  __shared__ double sc2[2];
  __shared__ int updflag;
  unsigned* cnt = (unsigned*)(ws + OFF_CNTD);
  const int c0 = chunk * 64;
  if (tid < M2Q) uvec[tid] = ws[OFF_USOL + b * M2Q + tid];
  __syncthreads();
  const int kk = tid & 63, rq = tid >> 6;
  const int k = c0 + kk;
  const int kg = (k < NXQ) ? k : (NXQ - 1);
  {
    const float* gp = G2 + (rq * 16) * NXQ + kg;
    double acc = 0.0;
#pragma unroll
    for (int j = 0; j < 16; ++j) acc = fma((double)gp[j * NXQ], uvec[rq * 16 + j], acc);
    part[rq * 64 + kk] = acc;
  }
  __syncthreads();
  double lmin = 1e300;
  if (tid < 64) {
    const int k2 = c0 + tid;
    if (k2 < NXQ) {
      double w = 0.0;
#pragma unroll
      for (int q = 0; q < 8; ++q) w += part[q * 64 + tid];
      const double dz = ws[OFF_Y + b * NXQ + k2] - ws[OFF_AINV + b * NXQ + k2] * w;
      ws[OFF_DZS + b * 768 + k2] = dz;
      const double dsi = dz - ws[OFF_RP + b * MQ + k2];
      const double dlami = ws[OFF_V + b * MQ + k2] - ws[OFF_D + b * MQ + k2] * dz;
      if (dsi < 0.0)   lmin = fmin(lmin, -ws[OFF_S + b * MQ + k2] / dsi);
      if (dlami < 0.0) lmin = fmin(lmin, -ws[OFF_LAM + b * MQ + k2] / dlami);
    }
    lmin = wred_min(lmin);
    if (tid == 0) ws[OFF_CMIN + chunk * BQ + b] = lmin;
  }
  __syncthreads();
  if (tid == 0) {
    __threadfence();
    const unsigned prev = __hip_atomic_fetch_add(&cnt[b], 1u, __ATOMIC_ACQ_REL, __HIP_MEMORY_SCOPE_AGENT);
    updflag = (prev == 11u) ? 1 : 0;
    if (updflag) __threadfence();
  }
  __syncthreads();
  if (!updflag) return;

  double* z    = ws + OFF_Z   + b * NXQ;
  double* s_   = ws + OFF_S   + b * MQ;
  double* lam_ = ws + OFF_LAM + b * MQ;
  double* dd   = ws + OFF_D   + b * MQ;
  double* rp   = ws + OFF_RP  + b * MQ;
  double* vv   = ws + OFF_V   + b * MQ;
  double* gz2  = ws + OFF_GZ2 + b * M2Q;
  if (tid == 0) {
    double m = 1e300;
#pragma unroll
    for (int c = 0; c < 13; ++c) m = fmin(m, ws[OFF_CMIN + c * BQ + b]);
    sc2[0] = fmin(1.0, 0.99 * m);
    __hip_atomic_store(&cnt[b], 0u, __ATOMIC_RELAXED, __HIP_MEMORY_SCOPE_AGENT);
  }
  __syncthreads();
  const double alpha = sc2[0];
  for (int i = tid; i < NXQ; i += 512) {
    const double dz = ws[OFF_DZS + b * 768 + i];
    s_[i]   += alpha * (dz - rp[i]);
    lam_[i] += alpha * (vv[i] - dd[i] * dz);
    const double zi = z[i] + alpha * dz;
    z[i] = zi;
    out[b * NXQ + i] = (float)zi;
  }
  if (tid < M2Q) {
    const int i = NXQ + tid;
    const double g = ws[OFF_G2B + b * M2Q + tid];
    s_[i]   += alpha * (-rp[i] - g);
    lam_[i] += alpha * (vv[i] + dd[i] * g);
    gz2[tid] += alpha * g;
  }
  __syncthreads();
  if (last) return;

  double musum = 0.0;
  for (int i = tid; i < MQ; i += 512) {
    const double si = s_[i], li = lam_[i];
    dd[i] = li / si;
    const double rpi = (i < NXQ) ? (si - z[i]) : (gz2[i - NXQ] + si - ws[OFF_H2 + i - NXQ]);
    rp[i] = rpi;
    musum += si * li;
  }
  musum = wred_sum(musum);
  if (lane == 0) red[wave] = musum;
  __syncthreads();
  if (tid == 0) {
    double t = 0.0;
#pragma unroll
    for (int w = 0; w < 8; ++w) t += red[w];
    sc2[1] = SIGMA_ * (t / (double)MQ);
  }
  __syncthreads();
  const double smu = sc2[1];
  for (int i = tid; i < MQ; i += 512) {
    const double si = s_[i], li = lam_[i];
    const double vi = smu / si - li + dd[i] * rp[i];
    vv[i] = vi;
    if (i >= NXQ) ws[OFF_Q2 + b * M2Q + (i - NXQ)] = li + vi;
    else ws[OFF_AINV + b * NXQ + i] = 1.0 / (QPEN_ + dd[i]);
  }
}

extern "C" void kernel_launch(void* const* d_in, const int* in_sizes, int n_in,
                              void* d_out, int out_size, void* d_ws, size_t ws_size,
                              hipStream_t stream) {
  const float* puzzles = (const float*)d_in[0];
  const float* G2      = (const float*)d_in[1];
  const float* z2      = (const float*)d_in[2];
  const float* s2      = (const float*)d_in[3];
  float* out = (float*)d_out;
  double* ws = (double*)d_ws;

  (void)hipFuncSetAttribute(reinterpret_cast<const void*>(&solve_kernel),
                            hipFuncAttributeMaxDynamicSharedMemorySize, SH_SOLVE);
  (void)hipFuncSetAttribute(reinterpret_cast<const void*>(&ps_kernel),
                            hipFuncAttributeMaxDynamicSharedMemorySize, SH_PS);

  init_kernel<<<dim3(16 + M2Q), dim3(512), 0, stream>>>(puzzles, G2, z2, s2, ws);
  ps_kernel<<<dim3(16, BQ), dim3(512), SH_PS, stream>>>(G2, ws);
  for (int it = 0; it < 10; ++it) {
    solve_kernel<<<dim3(BQ), dim3(512), SH_SOLVE, stream>>>(ws);
    dzupd_kernel<<<dim3(12, BQ), dim3(512), 0, stream>>>(G2, ws, out, (it == 9) ? 1 : 0);
    if (it < 9)
      ps_kernel<<<dim3(16, BQ), dim3(512), SH_PS, stream>>>(G2, ws);
  }
}

// Round 12
// 1238.986 us; speedup vs baseline: 1.1248x; 1.1248x over previous
//
#include <hip/hip_runtime.h>
#include <math.h>

#define NXQ 729
#define M2Q 128
#define MQ  857
#define BQ  16
#define QPEN_ 0.1
#define SIGMA_ 0.1

typedef double d4 __attribute__((ext_vector_type(4)));

// workspace offsets (in doubles)
constexpr int OFF_P    = 0;                        // 16x729
constexpr int OFF_H2   = OFF_P + BQ*NXQ;           // 128
constexpr int OFF_Z    = OFF_H2 + M2Q;             // 16x729
constexpr int OFF_S    = OFF_Z + BQ*NXQ;           // 16x857
constexpr int OFF_LAM  = OFF_S + BQ*MQ;            // 16x857
constexpr int OFF_D    = OFF_LAM + BQ*MQ;          // 16x857
constexpr int OFF_RP   = OFF_D + BQ*MQ;            // 16x857
constexpr int OFF_V    = OFF_RP + BQ*MQ;           // 16x857
constexpr int OFF_AINV = OFF_V + BQ*MQ;            // 16x729
constexpr int OFF_Y    = OFF_AINV + BQ*NXQ;        // 16x729
constexpr int OFF_GZ2  = OFF_Y + BQ*NXQ;           // 16x128
constexpr int OFF_Q2   = OFF_GZ2 + BQ*M2Q;         // 16x128
constexpr int OFF_USOL = OFF_Q2 + BQ*M2Q;          // 16x128
constexpr int OFF_G2B  = OFF_USOL + BQ*M2Q;        // 16x128
constexpr int OFF_TP   = OFF_G2B + BQ*M2Q;         // 12x16x128 t partials
constexpr int OFF_CMIN = OFF_TP + 12*BQ*M2Q;       // 13x16 alpha partial mins
constexpr int OFF_SG   = OFF_CMIN + 13*BQ + 48;    // 16x128x128 S matrices (lower tiles only)
constexpr int OFF_DZS  = OFF_SG;                   // 16x768 ALIASES SG prefix
                                                   // (safe: solve reads only the 10 lower tiles,
                                                   //  consumed before dzupd writes; ps rewrites)
constexpr int OFF_CNTD = OFF_SG + BQ*M2Q*M2Q;      // dz->upd counters (16 uints)

// solve LDS layout (doubles) — R9 verbatim
constexpr int L_SL   = 0;                  // 128 x 129 = 16512
constexpr int L_US   = 16512;              // 128
constexpr int L_INVD = 16640;              // 128
constexpr int L_RED2 = 16768;              // 512
constexpr int L_RED  = 17280;              // 8
constexpr int SH_SOLVE = (17288) * 8;      // 138304 B
constexpr int SH_PS    = 4 * 2176 * 8;     // 69632 B

__device__ __forceinline__ double wred_sum(double v) {
#pragma unroll
  for (int off = 32; off > 0; off >>= 1) v += __shfl_down(v, off, 64);
  return v;
}
__device__ __forceinline__ double wred_min(double v) {
#pragma unroll
  for (int off = 32; off > 0; off >>= 1) v = fmin(v, __shfl_down(v, off, 64));
  return v;
}
__device__ __forceinline__ double rsqrt64(double x) { return rsqrt(x); }

// ---------------------------------------------------------------------------
// init: grid 144 x 512 (R9 verbatim)
// ---------------------------------------------------------------------------
__global__ __launch_bounds__(512)
void init_kernel(const float* __restrict__ puzzles, const float* __restrict__ G2,
                 const float* __restrict__ z2in, const float* __restrict__ s2in,
                 double* __restrict__ ws) {
  const int blk = blockIdx.x;
  const int tid = threadIdx.x, wave = tid >> 6, lane = tid & 63;
  __shared__ double sm[32];
  if (blk < BQ) {
    const int bb = blk;
    for (int i = tid; i < NXQ; i += 512) {
      ws[OFF_P + bb * NXQ + i] = -(double)puzzles[bb * NXQ + i];
      ws[OFF_Z + bb * NXQ + i] = 0.0;
      ws[OFF_AINV + bb * NXQ + i] = 1.0 / (QPEN_ + 1.0);
      ws[OFF_RP + bb * MQ + i] = 1.0;
      ws[OFF_V + bb * MQ + i] = SIGMA_;
    }
    for (int i = tid; i < MQ; i += 512) {
      ws[OFF_S + bb * MQ + i] = 1.0;
      ws[OFF_LAM + bb * MQ + i] = 1.0;
      ws[OFF_D + bb * MQ + i] = 1.0;
    }
    if (tid < M2Q) ws[OFF_GZ2 + bb * M2Q + tid] = 0.0;
    if (tid == 0) ((unsigned*)(ws + OFF_CNTD))[bb] = 0u;
  } else {
    const int r = blk - 16;
    double acc = 0.0;
    for (int kx = tid; kx < NXQ; kx += 512)
      acc += (double)G2[r * NXQ + kx] * (double)z2in[kx];
    acc = wred_sum(acc);
    if (lane == 0) sm[wave] = acc;
    __syncthreads();
    if (tid == 0) {
      double t = 0.0;
#pragma unroll
      for (int w = 0; w < 8; ++w) t += sm[w];
      const double h2r = t + (double)s2in[r];
      ws[OFF_H2 + r] = h2r;
      sm[16] = h2r;
    }
    __syncthreads();
    if (tid < BQ) {
      const double rp2 = 1.0 - sm[16];
      ws[OFF_RP + tid * MQ + NXQ + r] = rp2;
      ws[OFF_V  + tid * MQ + NXQ + r] = rp2 - 0.9;
      ws[OFF_Q2 + tid * M2Q + r] = rp2 + 0.1;
    }
  }
}

// ---------------------------------------------------------------------------
// ps: grid (12 chunks, 16 batches) x 512.
// All 12 blocks: prep chunk (rhs,y + t partials).
// Blocks 0..9: sbuild of the 10 LOWER-TRIANGLE 32x32 tiles of symmetric S.
// ---------------------------------------------------------------------------
__global__ __launch_bounds__(512)
void ps_kernel(const float* __restrict__ G2, double* __restrict__ ws) {
  const int tile = blockIdx.x, b = blockIdx.y;
  const int tid = threadIdx.x, wave = tid >> 6, lane = tid & 63;
  extern __shared__ double sm[];

  // ---- prep chunk (R9 verbatim; grid x == 12 so no gate needed) ----
  {
    double* uvec = sm;
    double* part = sm + 128;
    double* yl   = sm + 640;
    const int c0 = tile * 64;
    if (tid < M2Q) uvec[tid] = ws[OFF_Q2 + b * M2Q + tid];
    __syncthreads();
    const int kk = tid & 63, rq = tid >> 6;
    const int k = c0 + kk;
    const int kg = (k < NXQ) ? k : (NXQ - 1);
    {
      const float* gp = G2 + (rq * 16) * NXQ + kg;
      double acc = 0.0;
#pragma unroll
      for (int j = 0; j < 16; ++j) acc = fma((double)gp[j * NXQ], uvec[rq * 16 + j], acc);
      part[rq * 64 + kk] = acc;
    }
    __syncthreads();
    if (tid < 64) {
      const int k2 = c0 + tid;
      double y = 0.0;
      if (k2 < NXQ) {
        double w = 0.0;
#pragma unroll
        for (int q = 0; q < 8; ++q) w += part[q * 64 + tid];
        const double rhsk = -(QPEN_ * ws[OFF_Z + b * NXQ + k2] + ws[OFF_P + b * NXQ + k2]
                              - ws[OFF_LAM + b * MQ + k2] - ws[OFF_V + b * MQ + k2] + w);
        y = ws[OFF_AINV + b * NXQ + k2] * rhsk;
        ws[OFF_Y + b * NXQ + k2] = y;
      }
      yl[tid] = y;
    }
    __syncthreads();
    const double yv = yl[lane];
#pragma unroll
    for (int jr = 0; jr < 16; ++jr) {
      const int r = (tid >> 6) * 16 + jr;
      double v = (double)G2[r * NXQ + kg] * yv;
      v = wred_sum(v);
      if (lane == 0) ws[OFF_TP + (tile * BQ + b) * M2Q + r] = v;
    }
    __syncthreads();
  }

  // ---- sbuild: lower-triangle tiles only ----
  if (tile < 10) {
    // tile -> (row,col) in 4x4 tile grid, lower triangle
    const int TRI_R[10] = {0,1,1,2,2,2,3,3,3,3};
    const int TRI_C[10] = {0,0,1,0,1,2,0,1,2,3};
    const int R0 = TRI_R[tile] * 32, C0 = TRI_C[tile] * 32;
    double* As = sm + wave * 2176;
    double* Bs = As + 1088;
    const double* __restrict__ ainv = ws + OFF_AINV + b * NXQ;
    const int k0w = wave * 183;
    const int kend = min(k0w + 183, NXQ);
    const int rg4 = (lane >> 3) * 4, cg4 = (lane & 7) * 4;
    double acc[4][4];
#pragma unroll
    for (int i = 0; i < 4; ++i)
#pragma unroll
      for (int j = 0; j < 4; ++j) acc[i][j] = 0.0;

    const int kk2 = lane & 31;
    for (int ch = 0; ch < 6; ++ch) {
      __syncthreads();
      if (wave < 4) {
        const int k = k0w + ch * 32 + kk2;
        const bool ok = (k < kend);
        const double aik = ok ? ainv[k] : 0.0;
#pragma unroll
        for (int it = 0; it < 16; ++it) {
          const int rr = (it << 1) | (lane >> 5);
          double av = 0.0, bv = 0.0;
          if (ok) {
            av = (double)G2[(R0 + rr) * NXQ + k] * aik;
            bv = (double)G2[(C0 + rr) * NXQ + k];
          }
          As[kk2 * 34 + rr] = av;
          Bs[kk2 * 34 + rr] = bv;
        }
      }
      __syncthreads();
      if (wave < 4) {
#pragma unroll 8
        for (int q = 0; q < 32; ++q) {
          const double a0 = As[q*34 + rg4 + 0], a1 = As[q*34 + rg4 + 1],
                       a2 = As[q*34 + rg4 + 2], a3 = As[q*34 + rg4 + 3];
          const double b0 = Bs[q*34 + cg4 + 0], b1 = Bs[q*34 + cg4 + 1],
                       b2 = Bs[q*34 + cg4 + 2], b3 = Bs[q*34 + cg4 + 3];
          acc[0][0] += a0*b0; acc[0][1] += a0*b1; acc[0][2] += a0*b2; acc[0][3] += a0*b3;
          acc[1][0] += a1*b0; acc[1][1] += a1*b1; acc[1][2] += a1*b2; acc[1][3] += a1*b3;
          acc[2][0] += a2*b0; acc[2][1] += a2*b1; acc[2][2] += a2*b2; acc[2][3] += a2*b3;
          acc[3][0] += a3*b0; acc[3][1] += a3*b1; acc[3][2] += a3*b2; acc[3][3] += a3*b3;
        }
      }
    }
    __syncthreads();
    if (wave < 4) {
#pragma unroll
      for (int i = 0; i < 4; ++i)
#pragma unroll
        for (int j = 0; j < 4; ++j)
          As[(rg4 + i) * 32 + cg4 + j] = acc[i][j];
    }
    __syncthreads();
    double* __restrict__ Sgb = ws + OFF_SG + b * (M2Q * M2Q);
    for (int idx = tid; idx < 1024; idx += 512) {
      const double v = sm[idx] + sm[2176 + idx] + sm[4352 + idx] + sm[6528 + idx];
      Sgb[(R0 + (idx >> 5)) * M2Q + C0 + (idx & 31)] = v;
    }
  }
}

// ---------------------------------------------------------------------------
// solve: 16 blocks x 512. R9-verbatim factorization; Phase A loads the 10
// lower tiles and mirrors off-diagonal ones into the upper half of LDS.
// ---------------------------------------------------------------------------
__global__ __launch_bounds__(512, 2)
void solve_kernel(double* __restrict__ ws) {
  const int b = blockIdx.x;
  const int tid = threadIdx.x, wave = tid >> 6, lane = tid & 63;
  extern __shared__ double sm[];
  double (*Sl)[129] = (double(*)[129])(sm + L_SL);
  double* us   = sm + L_US;
  double* invd = sm + L_INVD;
  double* red2 = sm + L_RED2;
  double* red  = sm + L_RED;
  double* s_   = ws + OFF_S   + b * MQ;
  double* lam_ = ws + OFF_LAM + b * MQ;
  double* Sgb  = ws + OFF_SG  + b * M2Q * M2Q;

  // ---- Phase A: load 10 lower tiles, mirror the 6 off-diagonal ones ----
#pragma unroll
  for (int t = 0; t < 10; ++t) {
    const int TRI_R[10] = {0,1,1,2,2,2,3,3,3,3};
    const int TRI_C[10] = {0,0,1,0,1,2,0,1,2,3};
    const int R0 = TRI_R[t] * 32, C0 = TRI_C[t] * 32;
    const bool offd = (R0 != C0);
    for (int e = tid; e < 1024; e += 512) {
      const int r = e >> 5, c = e & 31;
      const double v = Sgb[(R0 + r) * M2Q + C0 + c];
      Sl[R0 + r][C0 + c] = v;
      if (offd) Sl[C0 + c][R0 + r] = v;
    }
  }
  if (tid < M2Q) {
    double t = 0.0;
#pragma unroll
    for (int c = 0; c < 12; ++c) t += ws[OFF_TP + (c * BQ + b) * M2Q + tid];
    us[tid] = t;
  }
  __syncthreads();
  if (tid < M2Q) Sl[tid][tid] += s_[NXQ + tid] / lam_[NXQ + tid];
  __syncthreads();

  // runtime probe of f64 MFMA C/D register->(row,col) mapping (verified R4)
  int rowm[4], colm[4];
  {
    const int rc = lane & 15, kq = lane >> 4;
    const double avr = (kq == 0) ? (double)rc : 0.0;
    const double bv1 = (kq == 0) ? 1.0 : 0.0;
    const double av1 = (kq == 0) ? 1.0 : 0.0;
    const double bvc = (kq == 0) ? (double)rc : 0.0;
    d4 zero = {0.0, 0.0, 0.0, 0.0};
    d4 dr = __builtin_amdgcn_mfma_f64_16x16x4f64(avr, bv1, zero, 0, 0, 0);
    d4 dc = __builtin_amdgcn_mfma_f64_16x16x4f64(av1, bvc, zero, 0, 0, 0);
#pragma unroll
    for (int e = 0; e < 4; ++e) { rowm[e] = (int)dr[e]; colm[e] = (int)dc[e]; }
  }

  // blocked Cholesky (NB=16) with forward substitution as extra TRSM row
  for (int kb = 0; kb < 8; ++kb) {
    const int K0 = kb * 16, J0 = K0 + 16, T = 128 - J0;
    if (wave == 0 && lane < 16) {
      const int r = lane;
      double a[16];
#pragma unroll
      for (int c = 0; c < 16; ++c) a[c] = Sl[K0 + r][K0 + c];
#pragma unroll
      for (int c = 0; c < 16; ++c) {
        const double dcc = __shfl(a[c], c, 64);
        const double rs = rsqrt64(dcc);
        a[c] *= rs;
        if (lane == c) invd[K0 + c] = rs;
#pragma unroll
        for (int k2 = c + 1; k2 < 16; ++k2) {
          const double lkc = __shfl(a[c], k2, 64);
          a[k2] = fma(-a[c], lkc, a[k2]);
        }
      }
#pragma unroll
      for (int c = 0; c < 16; ++c) Sl[K0 + r][K0 + c] = a[c];
    }
    __syncthreads();

    if (tid <= T) {
      const bool isU = (tid == T);
      double l[16];
      if (isU) {
#pragma unroll
        for (int c = 0; c < 16; ++c) l[c] = us[K0 + c];
      } else {
#pragma unroll
        for (int c = 0; c < 16; ++c) l[c] = Sl[J0 + tid][K0 + c];
      }
#pragma unroll
      for (int c = 0; c < 16; ++c) {
        const double lc = l[c] * invd[K0 + c];
        l[c] = lc;
#pragma unroll
        for (int k2 = c + 1; k2 < 16; ++k2)
          l[k2] = fma(-lc, Sl[K0 + k2][K0 + c], l[k2]);
      }
      if (isU) {
#pragma unroll
        for (int c = 0; c < 16; ++c) us[K0 + c] = l[c];
      } else {
#pragma unroll
        for (int c = 0; c < 16; ++c) Sl[J0 + tid][K0 + c] = l[c];
      }
    }
    __syncthreads();

    if (kb < 7) {
      if (tid < T) {
        double acc = 0.0;
#pragma unroll
        for (int c = 0; c < 16; ++c) acc = fma(Sl[J0 + tid][K0 + c], us[K0 + c], acc);
        us[J0 + tid] -= acc;
      }
      const int Tb = 7 - kb;
      const int rc = lane & 15, kq = lane >> 4;
      for (int idx = wave; idx < Tb * Tb; idx += 8) {
        const int i0 = J0 + (idx / Tb) * 16;
        const int j0 = J0 + (idx % Tb) * 16;
        d4 acc;
#pragma unroll
        for (int e = 0; e < 4; ++e) acc[e] = Sl[i0 + rowm[e]][j0 + colm[e]];
#pragma unroll
        for (int m = 0; m < 4; ++m) {
          const double av = -Sl[i0 + rc][K0 + 4 * m + kq];
          const double bv =  Sl[j0 + rc][K0 + 4 * m + kq];
          acc = __builtin_amdgcn_mfma_f64_16x16x4f64(av, bv, acc, 0, 0, 0);
        }
#pragma unroll
        for (int e = 0; e < 4; ++e) Sl[i0 + rowm[e]][j0 + colm[e]] = acc[e];
      }
    }
    __syncthreads();
  }

  // backward substitution L^T u = u'
  for (int kb = 7; kb >= 0; --kb) {
    const int K0 = kb * 16;
    if (kb < 7) {
      const int c = tid & 15, ch = tid >> 4;  // ch 0..31
      double part = 0.0;
      for (int k = K0 + 16 + ch; k < 128; k += 32) part = fma(Sl[k][K0 + c], us[k], part);
      red2[c * 32 + ch] = part;
      __syncthreads();
      if (tid < 16) {
        double acc = 0.0;
#pragma unroll
        for (int q = 0; q < 32; ++q) acc += red2[tid * 32 + q];
        us[K0 + tid] -= acc;
      }
      __syncthreads();
    }
    if (wave == 0 && lane < 16) {
      const int j = lane;
      double colv[16];
#pragma unroll
      for (int c = 0; c < 16; ++c) colv[c] = Sl[K0 + c][K0 + j];
      double x = us[K0 + j];
      const double iv = invd[K0 + j];
#pragma unroll
      for (int cc = 0; cc < 16; ++cc) {
        const int c = 15 - cc;
        const double xiv = x * iv;
        const double uc = __shfl(xiv, c, 64);
        if (j == c) x = xiv;
        else if (j < c) x = fma(-colv[c], uc, x);
      }
      us[K0 + j] = x;
    }
    __syncthreads();
  }

  // tail: write u, g2b = D2inv*u; m2-part ratio min -> cmin slot 12
  double lmin = 1e300;
  if (tid < M2Q) {
    const double u = us[tid];
    ws[OFF_USOL + b * M2Q + tid] = u;
    const double g = (s_[NXQ + tid] / lam_[NXQ + tid]) * u;
    ws[OFF_G2B + b * M2Q + tid] = g;
    const int i = NXQ + tid;
    const double dsi = -ws[OFF_RP + b * MQ + i] - g;
    const double dlami = ws[OFF_V + b * MQ + i] + ws[OFF_D + b * MQ + i] * g;
    if (dsi < 0.0)   lmin = fmin(lmin, -s_[i] / dsi);
    if (dlami < 0.0) lmin = fmin(lmin, -lam_[i] / dlami);
  }
  if (tid < 128) {
    lmin = wred_min(lmin);
    if (lane == 0) red[wave] = lmin;
  }
  __syncthreads();
  if (tid == 0) ws[OFF_CMIN + 12 * BQ + b] = fmin(red[0], red[1]);
}

// ---------------------------------------------------------------------------
// dzupd: grid (12 chunks, 16 batches) x 512 (R9 verbatim)
// ---------------------------------------------------------------------------
__global__ __launch_bounds__(512)
void dzupd_kernel(const float* __restrict__ G2, double* __restrict__ ws,
                  float* __restrict__ out, const int last) {
  const int chunk = blockIdx.x, b = blockIdx.y;
  const int tid = threadIdx.x, lane = tid & 63, wave = tid >> 6;
  __shared__ double uvec[128];
  __shared__ double part[512];
  __shared__ double red[8];
  __shared__ double sc2[2];
  __shared__ int updflag;
  unsigned* cnt = (unsigned*)(ws + OFF_CNTD);
  const int c0 = chunk * 64;
  if (tid < M2Q) uvec[tid] = ws[OFF_USOL + b * M2Q + tid];
  __syncthreads();
  const int kk = tid & 63, rq = tid >> 6;
  const int k = c0 + kk;
  const int kg = (k < NXQ) ? k : (NXQ - 1);
  {
    const float* gp = G2 + (rq * 16) * NXQ + kg;
    double acc = 0.0;
#pragma unroll
    for (int j = 0; j < 16; ++j) acc = fma((double)gp[j * NXQ], uvec[rq * 16 + j], acc);
    part[rq * 64 + kk] = acc;
  }
  __syncthreads();
  double lmin = 1e300;
  if (tid < 64) {
    const int k2 = c0 + tid;
    if (k2 < NXQ) {
      double w = 0.0;
#pragma unroll
      for (int q = 0; q < 8; ++q) w += part[q * 64 + tid];
      const double dz = ws[OFF_Y + b * NXQ + k2] - ws[OFF_AINV + b * NXQ + k2] * w;
      ws[OFF_DZS + b * 768 + k2] = dz;
      const double dsi = dz - ws[OFF_RP + b * MQ + k2];
      const double dlami = ws[OFF_V + b * MQ + k2] - ws[OFF_D + b * MQ + k2] * dz;
      if (dsi < 0.0)   lmin = fmin(lmin, -ws[OFF_S + b * MQ + k2] / dsi);
      if (dlami < 0.0) lmin = fmin(lmin, -ws[OFF_LAM + b * MQ + k2] / dlami);
    }
    lmin = wred_min(lmin);
    if (tid == 0) ws[OFF_CMIN + chunk * BQ + b] = lmin;
  }
  __syncthreads();
  if (tid == 0) {
    __threadfence();
    const unsigned prev = __hip_atomic_fetch_add(&cnt[b], 1u, __ATOMIC_ACQ_REL, __HIP_MEMORY_SCOPE_AGENT);
    updflag = (prev == 11u) ? 1 : 0;
    if (updflag) __threadfence();
  }
  __syncthreads();
  if (!updflag) return;

  double* z    = ws + OFF_Z   + b * NXQ;
  double* s_   = ws + OFF_S   + b * MQ;
  double* lam_ = ws + OFF_LAM + b * MQ;
  double* dd   = ws + OFF_D   + b * MQ;
  double* rp   = ws + OFF_RP  + b * MQ;
  double* vv   = ws + OFF_V   + b * MQ;
  double* gz2  = ws + OFF_GZ2 + b * M2Q;
  if (tid == 0) {
    double m = 1e300;
#pragma unroll
    for (int c = 0; c < 13; ++c) m = fmin(m, ws[OFF_CMIN + c * BQ + b]);
    sc2[0] = fmin(1.0, 0.99 * m);
    __hip_atomic_store(&cnt[b], 0u, __ATOMIC_RELAXED, __HIP_MEMORY_SCOPE_AGENT);
  }
  __syncthreads();
  const double alpha = sc2[0];
  for (int i = tid; i < NXQ; i += 512) {
    const double dz = ws[OFF_DZS + b * 768 + i];
    s_[i]   += alpha * (dz - rp[i]);
    lam_[i] += alpha * (vv[i] - dd[i] * dz);
    const double zi = z[i] + alpha * dz;
    z[i] = zi;
    out[b * NXQ + i] = (float)zi;
  }
  if (tid < M2Q) {
    const int i = NXQ + tid;
    const double g = ws[OFF_G2B + b * M2Q + tid];
    s_[i]   += alpha * (-rp[i] - g);
    lam_[i] += alpha * (vv[i] + dd[i] * g);
    gz2[tid] += alpha * g;
  }
  __syncthreads();
  if (last) return;

  double musum = 0.0;
  for (int i = tid; i < MQ; i += 512) {
    const double si = s_[i], li = lam_[i];
    dd[i] = li / si;
    const double rpi = (i < NXQ) ? (si - z[i]) : (gz2[i - NXQ] + si - ws[OFF_H2 + i - NXQ]);
    rp[i] = rpi;
    musum += si * li;
  }
  musum = wred_sum(musum);
  if (lane == 0) red[wave] = musum;
  __syncthreads();
  if (tid == 0) {
    double t = 0.0;
#pragma unroll
    for (int w = 0; w < 8; ++w) t += red[w];
    sc2[1] = SIGMA_ * (t / (double)MQ);
  }
  __syncthreads();
  const double smu = sc2[1];
  for (int i = tid; i < MQ; i += 512) {
    const double si = s_[i], li = lam_[i];
    const double vi = smu / si - li + dd[i] * rp[i];
    vv[i] = vi;
    if (i >= NXQ) ws[OFF_Q2 + b * M2Q + (i - NXQ)] = li + vi;
    else ws[OFF_AINV + b * NXQ + i] = 1.0 / (QPEN_ + dd[i]);
  }
}

extern "C" void kernel_launch(void* const* d_in, const int* in_sizes, int n_in,
                              void* d_out, int out_size, void* d_ws, size_t ws_size,
                              hipStream_t stream) {
  const float* puzzles = (const float*)d_in[0];
  const float* G2      = (const float*)d_in[1];
  const float* z2      = (const float*)d_in[2];
  const float* s2      = (const float*)d_in[3];
  float* out = (float*)d_out;
  double* ws = (double*)d_ws;

  (void)hipFuncSetAttribute(reinterpret_cast<const void*>(&solve_kernel),
                            hipFuncAttributeMaxDynamicSharedMemorySize, SH_SOLVE);
  (void)hipFuncSetAttribute(reinterpret_cast<const void*>(&ps_kernel),
                            hipFuncAttributeMaxDynamicSharedMemorySize, SH_PS);

  init_kernel<<<dim3(16 + M2Q), dim3(512), 0, stream>>>(puzzles, G2, z2, s2, ws);
  ps_kernel<<<dim3(12, BQ), dim3(512), SH_PS, stream>>>(G2, ws);
  for (int it = 0; it < 10; ++it) {
    solve_kernel<<<dim3(BQ), dim3(512), SH_SOLVE, stream>>>(ws);
    dzupd_kernel<<<dim3(12, BQ), dim3(512), 0, stream>>>(G2, ws, out, (it == 9) ? 1 : 0);
    if (it < 9)
      ps_kernel<<<dim3(12, BQ), dim3(512), SH_PS, stream>>>(G2, ws);
  }
}

// Round 13
// 1168.259 us; speedup vs baseline: 1.1929x; 1.0605x over previous
//
#include <hip/hip_runtime.h>
#include <math.h>

#define NXQ 729
#define M2Q 128
#define MQ  857
#define BQ  16
#define QPEN_ 0.1
#define SIGMA_ 0.1

typedef double d4 __attribute__((ext_vector_type(4)));

// workspace offsets (in doubles)
constexpr int OFF_P    = 0;                        // 16x729
constexpr int OFF_H2   = OFF_P + BQ*NXQ;           // 128
constexpr int OFF_Q2   = OFF_H2 + M2Q;             // 16x128 (init -> pre-loop ps only)
constexpr int OFF_USOL = OFF_Q2 + BQ*M2Q;          // 16x128
constexpr int OFF_G2B  = OFF_USOL + BQ*M2Q;        // 16x128
constexpr int OFF_TP   = OFF_G2B + BQ*M2Q;         // 12x16x128 t partials
// ping-pong state: 2 sets x 16 batches x STB
constexpr int ST_Z    = 0;      // 729
constexpr int ST_S    = 729;    // 857
constexpr int ST_LAM  = 1586;   // 857
constexpr int ST_RP   = 2443;   // 857
constexpr int ST_V    = 3300;   // 857
constexpr int ST_AINV = 4157;   // 729
constexpr int ST_Y    = 4886;   // 729
constexpr int ST_GZ   = 5615;   // 128
constexpr int STB     = 5743;
constexpr int OFF_ST  = OFF_TP + 12*BQ*M2Q;
constexpr int OFF_SG  = OFF_ST + 2*BQ*STB;         // 16 x 10 lower tiles x 1024, tile-major

// solve LDS layout (doubles)
constexpr int L_SL   = 0;                  // 128 x 129 = 16512
constexpr int L_US   = 16512;              // 128
constexpr int L_INVD = 16640;              // 128
constexpr int L_RED2 = 16768;              // 512
constexpr int L_RED  = 17280;              // 8
constexpr int SH_SOLVE = (17288) * 8;      // 138304 B

// dps LDS layout (doubles)
constexpr int D_DZ   = 0;      // 736
constexpr int D_UV   = 736;    // 128
constexpr int D_RED  = 864;    // 32
constexpr int D_SC   = 896;    // 8
constexpr int D_AINV = 904;    // 729
constexpr int D_Q2   = 1633;   // 128
constexpr int D_YL   = 1761;   // 64
constexpr int D_SN   = 1825;   // 857
constexpr int D_LN   = 2682;   // 857
constexpr int D_PART = 3539;   // 512
constexpr int D_AR   = 4096;   // sbuild arena: 4 x 2176 = 8704
constexpr int SH_DPS = (4096 + 8704) * 8;  // 102400 B
constexpr int SH_PS  = 4 * 2176 * 8;       // 69632 B

// lower-triangle tile tables (4x4 grid)
__device__ __constant__ int TRI_R[10] = {0,1,1,2,2,2,3,3,3,3};
__device__ __constant__ int TRI_C[10] = {0,0,1,0,1,2,0,1,2,3};

__device__ __forceinline__ double wred_sum(double v) {
#pragma unroll
  for (int off = 32; off > 0; off >>= 1) v += __shfl_down(v, off, 64);
  return v;
}
__device__ __forceinline__ double wred_min(double v) {
#pragma unroll
  for (int off = 32; off > 0; off >>= 1) v = fmin(v, __shfl_down(v, off, 64));
  return v;
}
// f32-seeded fp64 rsqrt (correctness-verified R10): ~1 ulp after 2 Newton steps
__device__ __forceinline__ double rsqrt64(double x) {
  double r = (double)rsqrtf((float)x);
  r = r * (1.5 - 0.5 * x * r * r);
  r = r * (1.5 - 0.5 * x * r * r);
  return r;
}

// ---------------------------------------------------------------------------
// init: grid 144 x 512. Blocks 0..15: per-batch set-0 state. 16..143: h2 row.
// ---------------------------------------------------------------------------
__global__ __launch_bounds__(512)
void init_kernel(const float* __restrict__ puzzles, const float* __restrict__ G2,
                 const float* __restrict__ z2in, const float* __restrict__ s2in,
                 double* __restrict__ ws) {
  const int blk = blockIdx.x;
  const int tid = threadIdx.x, wave = tid >> 6, lane = tid & 63;
  __shared__ double sm[32];
  if (blk < BQ) {
    const int bb = blk;
    double* st = ws + OFF_ST + bb * STB;   // set 0
    for (int i = tid; i < NXQ; i += 512) {
      ws[OFF_P + bb * NXQ + i] = -(double)puzzles[bb * NXQ + i];
      st[ST_Z + i] = 0.0;
      st[ST_AINV + i] = 1.0 / (QPEN_ + 1.0);
      st[ST_RP + i] = 1.0;     // s - z
      st[ST_V + i] = SIGMA_;   // 0.1/1 - 1 + 1
    }
    for (int i = tid; i < MQ; i += 512) { st[ST_S + i] = 1.0; st[ST_LAM + i] = 1.0; }
    if (tid < M2Q) st[ST_GZ + tid] = 0.0;
  } else {
    const int r = blk - 16;
    double acc = 0.0;
    for (int kx = tid; kx < NXQ; kx += 512)
      acc += (double)G2[r * NXQ + kx] * (double)z2in[kx];
    acc = wred_sum(acc);
    if (lane == 0) sm[wave] = acc;
    __syncthreads();
    if (tid == 0) {
      double t = 0.0;
#pragma unroll
      for (int w = 0; w < 8; ++w) t += sm[w];
      const double h2r = t + (double)s2in[r];
      ws[OFF_H2 + r] = h2r;
      sm[16] = h2r;
    }
    __syncthreads();
    if (tid < BQ) {
      double* st = ws + OFF_ST + tid * STB;   // set 0
      const double rp2 = 1.0 - sm[16];
      st[ST_RP + NXQ + r] = rp2;
      st[ST_V  + NXQ + r] = rp2 - 0.9;
      ws[OFF_Q2 + tid * M2Q + r] = rp2 + 0.1;
    }
  }
}

// ---------------------------------------------------------------------------
// sbuild core (shared by ps and dps): 32x32 lower tile -> SG tile-major.
// ainv provided via pointer (global for ps, LDS for dps).
// ---------------------------------------------------------------------------
__device__ __forceinline__ void sbuild_core(const float* __restrict__ G2,
                                            const double* __restrict__ ainv,
                                            double* __restrict__ arena,
                                            double* __restrict__ Sgb, const int tile) {
  const int tid = threadIdx.x, wave = tid >> 6, lane = tid & 63;
  const int R0 = TRI_R[tile] * 32, C0 = TRI_C[tile] * 32;
  double* As = arena + wave * 2176;
  double* Bs = As + 1088;
  const int k0w = wave * 183;
  const int kend = min(k0w + 183, NXQ);
  const int rg4 = (lane >> 3) * 4, cg4 = (lane & 7) * 4;
  double acc[4][4];
#pragma unroll
  for (int i = 0; i < 4; ++i)
#pragma unroll
    for (int j = 0; j < 4; ++j) acc[i][j] = 0.0;
  const int kk2 = lane & 31;
  for (int ch = 0; ch < 6; ++ch) {
    __syncthreads();
    if (wave < 4) {
      const int k = k0w + ch * 32 + kk2;
      const bool ok = (k < kend);
      const double aik = ok ? ainv[k] : 0.0;
#pragma unroll
      for (int it = 0; it < 16; ++it) {
        const int rr = (it << 1) | (lane >> 5);
        double av = 0.0, bv = 0.0;
        if (ok) {
          av = (double)G2[(R0 + rr) * NXQ + k] * aik;
          bv = (double)G2[(C0 + rr) * NXQ + k];
        }
        As[kk2 * 34 + rr] = av;
        Bs[kk2 * 34 + rr] = bv;
      }
    }
    __syncthreads();
    if (wave < 4) {
#pragma unroll 8
      for (int q = 0; q < 32; ++q) {
        const double a0 = As[q*34 + rg4 + 0], a1 = As[q*34 + rg4 + 1],
                     a2 = As[q*34 + rg4 + 2], a3 = As[q*34 + rg4 + 3];
        const double b0 = Bs[q*34 + cg4 + 0], b1 = Bs[q*34 + cg4 + 1],
                     b2 = Bs[q*34 + cg4 + 2], b3 = Bs[q*34 + cg4 + 3];
        acc[0][0] += a0*b0; acc[0][1] += a0*b1; acc[0][2] += a0*b2; acc[0][3] += a0*b3;
        acc[1][0] += a1*b0; acc[1][1] += a1*b1; acc[1][2] += a1*b2; acc[1][3] += a1*b3;
        acc[2][0] += a2*b0; acc[2][1] += a2*b1; acc[2][2] += a2*b2; acc[2][3] += a2*b3;
        acc[3][0] += a3*b0; acc[3][1] += a3*b1; acc[3][2] += a3*b2; acc[3][3] += a3*b3;
      }
    }
  }
  __syncthreads();
  if (wave < 4) {
#pragma unroll
    for (int i = 0; i < 4; ++i)
#pragma unroll
      for (int j = 0; j < 4; ++j)
        As[(rg4 + i) * 32 + cg4 + j] = acc[i][j];
  }
  __syncthreads();
  for (int idx = tid; idx < 1024; idx += 512) {
    const double v = arena[idx] + arena[2176 + idx] + arena[4352 + idx] + arena[6528 + idx];
    Sgb[tile * 1024 + idx] = v;
  }
}

// ---------------------------------------------------------------------------
// ps (pre-loop only): grid (12, 16) x 512. prep chunk + sbuild (tiles 0..9).
// ---------------------------------------------------------------------------
__global__ __launch_bounds__(512)
void ps_kernel(const float* __restrict__ G2, double* __restrict__ ws) {
  const int tile = blockIdx.x, b = blockIdx.y;
  const int tid = threadIdx.x, lane = tid & 63;
  extern __shared__ double sm[];
  double* st = ws + OFF_ST + b * STB;   // set 0

  {
    double* uvec = sm;
    double* part = sm + 128;
    double* yl   = sm + 640;
    const int c0 = tile * 64;
    if (tid < M2Q) uvec[tid] = ws[OFF_Q2 + b * M2Q + tid];
    __syncthreads();
    const int kk = tid & 63, rq = tid >> 6;
    const int k = c0 + kk;
    const int kg = (k < NXQ) ? k : (NXQ - 1);
    {
      const float* gp = G2 + (rq * 16) * NXQ + kg;
      double acc = 0.0;
#pragma unroll
      for (int j = 0; j < 16; ++j) acc = fma((double)gp[j * NXQ], uvec[rq * 16 + j], acc);
      part[rq * 64 + kk] = acc;
    }
    __syncthreads();
    if (tid < 64) {
      const int k2 = c0 + tid;
      double y = 0.0;
      if (k2 < NXQ) {
        double w = 0.0;
#pragma unroll
        for (int q = 0; q < 8; ++q) w += part[q * 64 + tid];
        const double rhsk = -(QPEN_ * st[ST_Z + k2] + ws[OFF_P + b * NXQ + k2]
                              - st[ST_LAM + k2] - st[ST_V + k2] + w);
        y = st[ST_AINV + k2] * rhsk;
        st[ST_Y + k2] = y;
      }
      yl[tid] = y;
    }
    __syncthreads();
    const double yv = yl[lane];
#pragma unroll
    for (int jr = 0; jr < 16; ++jr) {
      const int r = (tid >> 6) * 16 + jr;
      double v = (double)G2[r * NXQ + kg] * yv;
      v = wred_sum(v);
      if (lane == 0) ws[OFF_TP + (tile * BQ + b) * M2Q + r] = v;
    }
    __syncthreads();
  }
  if (tile < 10)
    sbuild_core(G2, st + ST_AINV, sm, ws + OFF_SG + b * 10240, tile);
}

// ---------------------------------------------------------------------------
// solve: 16 blocks x 512. R12-verbatim factorization; 10-tile Phase A.
// ---------------------------------------------------------------------------
__global__ __launch_bounds__(512, 1)
void solve_kernel(double* __restrict__ ws, const int ph) {
  const int b = blockIdx.x;
  const int tid = threadIdx.x, wave = tid >> 6, lane = tid & 63;
  extern __shared__ double sm[];
  double (*Sl)[129] = (double(*)[129])(sm + L_SL);
  double* us   = sm + L_US;
  double* invd = sm + L_INVD;
  double* red2 = sm + L_RED2;
  double* st   = ws + OFF_ST + ph * BQ * STB + b * STB;
  double* Sgb  = ws + OFF_SG + b * 10240;

#pragma unroll
  for (int t = 0; t < 10; ++t) {
    const int R0 = TRI_R[t] * 32, C0 = TRI_C[t] * 32;
    const bool offd = (R0 != C0);
    for (int e = tid; e < 1024; e += 512) {
      const int r = e >> 5, c = e & 31;
      const double v = Sgb[t * 1024 + e];
      Sl[R0 + r][C0 + c] = v;
      if (offd) Sl[C0 + c][R0 + r] = v;
    }
  }
  if (tid < M2Q) {
    double t = 0.0;
#pragma unroll
    for (int c = 0; c < 12; ++c) t += ws[OFF_TP + (c * BQ + b) * M2Q + tid];
    us[tid] = t;
  }
  __syncthreads();
  if (tid < M2Q) Sl[tid][tid] += st[ST_S + NXQ + tid] / st[ST_LAM + NXQ + tid];
  __syncthreads();

  int rowm[4], colm[4];
  {
    const int rc = lane & 15, kq = lane >> 4;
    const double avr = (kq == 0) ? (double)rc : 0.0;
    const double bv1 = (kq == 0) ? 1.0 : 0.0;
    const double av1 = (kq == 0) ? 1.0 : 0.0;
    const double bvc = (kq == 0) ? (double)rc : 0.0;
    d4 zero = {0.0, 0.0, 0.0, 0.0};
    d4 dr = __builtin_amdgcn_mfma_f64_16x16x4f64(avr, bv1, zero, 0, 0, 0);
    d4 dc = __builtin_amdgcn_mfma_f64_16x16x4f64(av1, bvc, zero, 0, 0, 0);
#pragma unroll
    for (int e = 0; e < 4; ++e) { rowm[e] = (int)dr[e]; colm[e] = (int)dc[e]; }
  }

  for (int kb = 0; kb < 8; ++kb) {
    const int K0 = kb * 16, J0 = K0 + 16, T = 128 - J0;
    if (wave == 0 && lane < 16) {
      const int r = lane;
      double a[16];
#pragma unroll
      for (int c = 0; c < 16; ++c) a[c] = Sl[K0 + r][K0 + c];
#pragma unroll
      for (int c = 0; c < 16; ++c) {
        const double dcc = __shfl(a[c], c, 64);
        const double rs = rsqrt64(dcc);
        a[c] *= rs;
        if (lane == c) invd[K0 + c] = rs;
#pragma unroll
        for (int k2 = c + 1; k2 < 16; ++k2) {
          const double lkc = __shfl(a[c], k2, 64);
          a[k2] = fma(-a[c], lkc, a[k2]);
        }
      }
#pragma unroll
      for (int c = 0; c < 16; ++c) Sl[K0 + r][K0 + c] = a[c];
    }
    __syncthreads();

    if (tid <= T) {
      const bool isU = (tid == T);
      double l[16];
      if (isU) {
#pragma unroll
        for (int c = 0; c < 16; ++c) l[c] = us[K0 + c];
      } else {
#pragma unroll
        for (int c = 0; c < 16; ++c) l[c] = Sl[J0 + tid][K0 + c];
      }
#pragma unroll
      for (int c = 0; c < 16; ++c) {
        const double lc = l[c] * invd[K0 + c];
        l[c] = lc;
#pragma unroll
        for (int k2 = c + 1; k2 < 16; ++k2)
          l[k2] = fma(-lc, Sl[K0 + k2][K0 + c], l[k2]);
      }
      if (isU) {
#pragma unroll
        for (int c = 0; c < 16; ++c) us[K0 + c] = l[c];
      } else {
#pragma unroll
        for (int c = 0; c < 16; ++c) Sl[J0 + tid][K0 + c] = l[c];
      }
    }
    __syncthreads();

    if (kb < 7) {
      if (tid < T) {
        double acc = 0.0;
#pragma unroll
        for (int c = 0; c < 16; ++c) acc = fma(Sl[J0 + tid][K0 + c], us[K0 + c], acc);
        us[J0 + tid] -= acc;
      }
      const int Tb = 7 - kb;
      const int rc = lane & 15, kq = lane >> 4;
      for (int idx = wave; idx < Tb * Tb; idx += 8) {
        const int i0 = J0 + (idx / Tb) * 16;
        const int j0 = J0 + (idx % Tb) * 16;
        d4 acc;
#pragma unroll
        for (int e = 0; e < 4; ++e) acc[e] = Sl[i0 + rowm[e]][j0 + colm[e]];
#pragma unroll
        for (int m = 0; m < 4; ++m) {
          const double av = -Sl[i0 + rc][K0 + 4 * m + kq];
          const double bv =  Sl[j0 + rc][K0 + 4 * m + kq];
          acc = __builtin_amdgcn_mfma_f64_16x16x4f64(av, bv, acc, 0, 0, 0);
        }
#pragma unroll
        for (int e = 0; e < 4; ++e) Sl[i0 + rowm[e]][j0 + colm[e]] = acc[e];
      }
    }
    __syncthreads();
  }

  for (int kb = 7; kb >= 0; --kb) {
    const int K0 = kb * 16;
    if (kb < 7) {
      const int c = tid & 15, ch = tid >> 4;
      double part = 0.0;
      for (int k = K0 + 16 + ch; k < 128; k += 32) part = fma(Sl[k][K0 + c], us[k], part);
      red2[c * 32 + ch] = part;
      __syncthreads();
      if (tid < 16) {
        double acc = 0.0;
#pragma unroll
        for (int q = 0; q < 32; ++q) acc += red2[tid * 32 + q];
        us[K0 + tid] -= acc;
      }
      __syncthreads();
    }
    if (wave == 0 && lane < 16) {
      const int j = lane;
      double colv[16];
#pragma unroll
      for (int c = 0; c < 16; ++c) colv[c] = Sl[K0 + c][K0 + j];
      double x = us[K0 + j];
      const double iv = invd[K0 + j];
#pragma unroll
      for (int cc = 0; cc < 16; ++cc) {
        const int c = 15 - cc;
        const double xiv = x * iv;
        const double uc = __shfl(xiv, c, 64);
        if (j == c) x = xiv;
        else if (j < c) x = fma(-colv[c], uc, x);
      }
      us[K0 + j] = x;
    }
    __syncthreads();
  }

  if (tid < M2Q) {
    const double u = us[tid];
    ws[OFF_USOL + b * M2Q + tid] = u;
    ws[OFF_G2B + b * M2Q + tid] = (st[ST_S + NXQ + tid] / st[ST_LAM + NXQ + tid]) * u;
  }
}

// ---------------------------------------------------------------------------
// dps: grid (12, 16) x 512. Redundant full dz + alpha + state update (own-slice
// global writes into the OTHER state set) + prep chunk + sbuild tile.
// ---------------------------------------------------------------------------
__global__ __launch_bounds__(512)
void dps_kernel(const float* __restrict__ G2, double* __restrict__ ws,
                float* __restrict__ out, const int ph, const int last) {
  const int chunk = blockIdx.x, b = blockIdx.y;
  const int tid = threadIdx.x, wave = tid >> 6, lane = tid & 63;
  extern __shared__ double sm[];
  double* dzl   = sm + D_DZ;
  double* uvec  = sm + D_UV;
  double* red   = sm + D_RED;
  double* sc    = sm + D_SC;
  double* ainvn = sm + D_AINV;
  double* q2l   = sm + D_Q2;
  double* yl    = sm + D_YL;
  double* snew  = sm + D_SN;
  double* lnew  = sm + D_LN;
  double* part  = sm + D_PART;
  const double* R = ws + OFF_ST + ph * BQ * STB + b * STB;
  double*       W = ws + OFF_ST + (1 - ph) * BQ * STB + b * STB;
  const double* g2b = ws + OFF_G2B + b * M2Q;
  const int c0 = chunk * 64;

  // Phase 0/1: full dz (coalesced column-parallel matvec)
  if (tid < M2Q) uvec[tid] = ws[OFF_USOL + b * M2Q + tid];
  __syncthreads();
  for (int k = tid; k < NXQ; k += 512) {
    double acc = 0.0;
    const float* gp = G2 + k;
#pragma unroll 8
    for (int r = 0; r < M2Q; ++r) acc = fma((double)gp[r * NXQ], uvec[r], acc);
    dzl[k] = R[ST_Y + k] - R[ST_AINV + k] * acc;
  }
  __syncthreads();

  // Phase 2: alpha (full, redundant, deterministic)
  double lmin = 1e300;
  for (int i = tid; i < MQ; i += 512) {
    const double si = R[ST_S + i], li = R[ST_LAM + i], di = li / si;
    double dsi, dlami;
    if (i < NXQ) {
      const double dz = dzl[i];
      dsi = dz - R[ST_RP + i];
      dlami = R[ST_V + i] - di * dz;
    } else {
      const double g = g2b[i - NXQ];
      dsi = -R[ST_RP + i] - g;
      dlami = R[ST_V + i] + di * g;
    }
    if (dsi < 0.0)   lmin = fmin(lmin, -si / dsi);
    if (dlami < 0.0) lmin = fmin(lmin, -li / dlami);
  }
  lmin = wred_min(lmin);
  if (lane == 0) red[wave] = lmin;
  __syncthreads();
  if (tid == 0) {
    double m = red[0];
#pragma unroll
    for (int w = 1; w < 8; ++w) m = fmin(m, red[w]);
    sc[0] = fmin(1.0, 0.99 * m);
  }
  __syncthreads();
  const double alpha = sc[0];

  if (last) {  // final iteration: just write out (own slice) and exit
    const int k2 = c0 + (tid & 63);
    if (tid < 64 && k2 < NXQ)
      out[b * NXQ + k2] = (float)(R[ST_Z + k2] + alpha * dzl[k2]);
    return;
  }

  // Phase 3: s/lam update (full, LDS) + musum (fixed order -> identical)
  double musum = 0.0;
  for (int i = tid; i < MQ; i += 512) {
    const double si = R[ST_S + i], li = R[ST_LAM + i], di = li / si;
    double dsi, dlami;
    if (i < NXQ) {
      const double dz = dzl[i];
      dsi = dz - R[ST_RP + i];
      dlami = R[ST_V + i] - di * dz;
    } else {
      const double g = g2b[i - NXQ];
      dsi = -R[ST_RP + i] - g;
      dlami = R[ST_V + i] + di * g;
    }
    const double sn = si + alpha * dsi, ln = li + alpha * dlami;
    snew[i] = sn; lnew[i] = ln;
    musum += sn * ln;
  }
  musum = wred_sum(musum);
  if (lane == 0) red[wave] = musum;
  __syncthreads();
  if (tid == 0) {
    double t = 0.0;
#pragma unroll
    for (int w = 0; w < 8; ++w) t += red[w];
    sc[1] = SIGMA_ * (t / (double)MQ);
  }
  __syncthreads();
  const double smu = sc[1];

  // Phase 4: derived state; own-slice writes to W
  for (int i = tid; i < MQ; i += 512) {
    const double sn = snew[i], ln = lnew[i], di = ln / sn;
    if (i < NXQ) {
      const double zn = R[ST_Z + i] + alpha * dzl[i];
      const double rpn = sn - zn;
      const double vn = smu / sn - ln + di * rpn;
      const double an = 1.0 / (QPEN_ + di);
      ainvn[i] = an;
      if ((i >> 6) == chunk) {
        W[ST_Z + i] = zn; W[ST_S + i] = sn; W[ST_LAM + i] = ln;
        W[ST_RP + i] = rpn; W[ST_V + i] = vn; W[ST_AINV + i] = an;
      }
    } else {
      const int m = i - NXQ;
      const double gzn = R[ST_GZ + m] + alpha * g2b[m];
      const double rpn = gzn + sn - ws[OFF_H2 + m];
      const double vn = smu / sn - ln + di * rpn;
      q2l[m] = ln + vn;
      if (chunk == 0) {
        W[ST_S + i] = sn; W[ST_LAM + i] = ln;
        W[ST_RP + i] = rpn; W[ST_V + i] = vn; W[ST_GZ + m] = gzn;
      }
    }
  }
  __syncthreads();

  // Phase 5: prep chunk (rhs, y, t partials) using LDS-local new state
  {
    const int kk = tid & 63, rq = tid >> 6;
    const int k = c0 + kk;
    const int kg = (k < NXQ) ? k : (NXQ - 1);
    {
      const float* gp = G2 + (rq * 16) * NXQ + kg;
      double acc = 0.0;
#pragma unroll
      for (int j = 0; j < 16; ++j) acc = fma((double)gp[j * NXQ], q2l[rq * 16 + j], acc);
      part[rq * 64 + kk] = acc;
    }
    __syncthreads();
    if (tid < 64) {
      const int k2 = c0 + tid;
      double y = 0.0;
      if (k2 < NXQ) {
        double w = 0.0;
#pragma unroll
        for (int q = 0; q < 8; ++q) w += part[q * 64 + tid];
        const double sn = snew[k2], ln = lnew[k2], di = ln / sn;
        const double zn = R[ST_Z + k2] + alpha * dzl[k2];
        const double rpn = sn - zn;
        const double vn = smu / sn - ln + di * rpn;
        const double rhsk = -(QPEN_ * zn + ws[OFF_P + b * NXQ + k2] - ln - vn + w);
        y = ainvn[k2] * rhsk;
        W[ST_Y + k2] = y;
      }
      yl[tid] = y;
    }
    __syncthreads();
    const double yv = yl[lane];
#pragma unroll
    for (int jr = 0; jr < 16; ++jr) {
      const int r = (tid >> 6) * 16 + jr;
      double v = (double)G2[r * NXQ + kg] * yv;
      v = wred_sum(v);
      if (lane == 0) ws[OFF_TP + (chunk * BQ + b) * M2Q + r] = v;
    }
    __syncthreads();
  }

  // Phase 6: sbuild (tiles 0..9) with LDS ainvn
  if (chunk < 10)
    sbuild_core(G2, ainvn, sm + D_AR, ws + OFF_SG + b * 10240, chunk);
}

extern "C" void kernel_launch(void* const* d_in, const int* in_sizes, int n_in,
                              void* d_out, int out_size, void* d_ws, size_t ws_size,
                              hipStream_t stream) {
  const float* puzzles = (const float*)d_in[0];
  const float* G2      = (const float*)d_in[1];
  const float* z2      = (const float*)d_in[2];
  const float* s2      = (const float*)d_in[3];
  float* out = (float*)d_out;
  double* ws = (double*)d_ws;

  (void)hipFuncSetAttribute(reinterpret_cast<const void*>(&solve_kernel),
                            hipFuncAttributeMaxDynamicSharedMemorySize, SH_SOLVE);
  (void)hipFuncSetAttribute(reinterpret_cast<const void*>(&ps_kernel),
                            hipFuncAttributeMaxDynamicSharedMemorySize, SH_PS);
  (void)hipFuncSetAttribute(reinterpret_cast<const void*>(&dps_kernel),
                            hipFuncAttributeMaxDynamicSharedMemorySize, SH_DPS);

  init_kernel<<<dim3(16 + M2Q), dim3(512), 0, stream>>>(puzzles, G2, z2, s2, ws);
  ps_kernel<<<dim3(12, BQ), dim3(512), SH_PS, stream>>>(G2, ws);
  for (int it = 0; it < 10; ++it) {
    const int ph = it & 1;
    solve_kernel<<<dim3(BQ), dim3(512), SH_SOLVE, stream>>>(ws, ph);
    dps_kernel<<<dim3(12, BQ), dim3(512), SH_DPS, stream>>>(G2, ws, out, ph, (it == 9) ? 1 : 0);
  }
}

// Round 14
// 1144.399 us; speedup vs baseline: 1.2177x; 1.0208x over previous
//
#include <hip/hip_runtime.h>
#include <math.h>

#define NXQ 729
#define M2Q 128
#define MQ  857
#define BQ  16
#define QPEN_ 0.1
#define SIGMA_ 0.1

typedef double d4 __attribute__((ext_vector_type(4)));

// workspace offsets (in doubles)
constexpr int OFF_P    = 0;                        // 16x729
constexpr int OFF_H2   = OFF_P + BQ*NXQ;           // 128
constexpr int OFF_Q2   = OFF_H2 + M2Q;             // 16x128 (init -> pre-loop ps only)
constexpr int OFF_TP   = OFF_Q2 + BQ*M2Q;          // 12x16x128 t partials
// ping-pong state: 2 sets x 16 batches x STB
constexpr int ST_Z    = 0;      // 729
constexpr int ST_S    = 729;    // 857
constexpr int ST_LAM  = 1586;   // 857
constexpr int ST_RP   = 2443;   // 857
constexpr int ST_V    = 3300;   // 857
constexpr int ST_AINV = 4157;   // 729
constexpr int ST_Y    = 4886;   // 729
constexpr int ST_GZ   = 5615;   // 128
constexpr int STB     = 5743;
constexpr int OFF_ST  = OFF_TP + 12*BQ*M2Q;
constexpr int OFF_SG  = OFF_ST + 2*BQ*STB;         // 16 x 10 lower tiles x 1024, tile-major

// fused-kernel LDS layout (doubles): solve region 0..16512 is reused (aliased)
// by the dps phases after the factorization is done.
constexpr int L_SL   = 0;                  // 128 x 129 = 16512 (solve only)
constexpr int L_US   = 16512;              // 128  (u — persists into dps phases)
constexpr int L_INVD = 16640;              // 128  (invd; reused as g2b after back-subst)
constexpr int L_RED2 = 16768;              // 512
constexpr int L_RED  = 17280;              // 8
constexpr int SH_FUSED = (17288) * 8;      // 138304 B -> 1 block/CU
// dps-phase aliases inside the dead Sl region:
constexpr int D_DZ   = 0;      // 736
constexpr int D_RED  = 736;    // 32
constexpr int D_SC   = 768;    // 8
constexpr int D_AINV = 776;    // 729
constexpr int D_Q2   = 1505;   // 128
constexpr int D_YL   = 1633;   // 64
constexpr int D_SN   = 1697;   // 857
constexpr int D_LN   = 2554;   // 857
constexpr int D_PART = 3411;   // 512
constexpr int D_AR   = 4096;   // sbuild arena 4x2176 = 8704 (ends 12800 < 16512)
constexpr int SH_PS  = 4 * 2176 * 8;       // 69632 B

__device__ __constant__ int TRI_R[10] = {0,1,1,2,2,2,3,3,3,3};
__device__ __constant__ int TRI_C[10] = {0,0,1,0,1,2,0,1,2,3};

__device__ __forceinline__ double wred_sum(double v) {
#pragma unroll
  for (int off = 32; off > 0; off >>= 1) v += __shfl_down(v, off, 64);
  return v;
}
__device__ __forceinline__ double wred_min(double v) {
#pragma unroll
  for (int off = 32; off > 0; off >>= 1) v = fmin(v, __shfl_down(v, off, 64));
  return v;
}
__device__ __forceinline__ double rsqrt64(double x) {
  double r = (double)rsqrtf((float)x);
  r = r * (1.5 - 0.5 * x * r * r);
  r = r * (1.5 - 0.5 * x * r * r);
  return r;
}

// ---------------------------------------------------------------------------
// init: grid 144 x 512 (R13 verbatim)
// ---------------------------------------------------------------------------
__global__ __launch_bounds__(512)
void init_kernel(const float* __restrict__ puzzles, const float* __restrict__ G2,
                 const float* __restrict__ z2in, const float* __restrict__ s2in,
                 double* __restrict__ ws) {
  const int blk = blockIdx.x;
  const int tid = threadIdx.x, wave = tid >> 6, lane = tid & 63;
  __shared__ double sm[32];
  if (blk < BQ) {
    const int bb = blk;
    double* st = ws + OFF_ST + bb * STB;   // set 0
    for (int i = tid; i < NXQ; i += 512) {
      ws[OFF_P + bb * NXQ + i] = -(double)puzzles[bb * NXQ + i];
      st[ST_Z + i] = 0.0;
      st[ST_AINV + i] = 1.0 / (QPEN_ + 1.0);
      st[ST_RP + i] = 1.0;
      st[ST_V + i] = SIGMA_;
    }
    for (int i = tid; i < MQ; i += 512) { st[ST_S + i] = 1.0; st[ST_LAM + i] = 1.0; }
    if (tid < M2Q) st[ST_GZ + tid] = 0.0;
  } else {
    const int r = blk - 16;
    double acc = 0.0;
    for (int kx = tid; kx < NXQ; kx += 512)
      acc += (double)G2[r * NXQ + kx] * (double)z2in[kx];
    acc = wred_sum(acc);
    if (lane == 0) sm[wave] = acc;
    __syncthreads();
    if (tid == 0) {
      double t = 0.0;
#pragma unroll
      for (int w = 0; w < 8; ++w) t += sm[w];
      const double h2r = t + (double)s2in[r];
      ws[OFF_H2 + r] = h2r;
      sm[16] = h2r;
    }
    __syncthreads();
    if (tid < BQ) {
      double* st = ws + OFF_ST + tid * STB;
      const double rp2 = 1.0 - sm[16];
      st[ST_RP + NXQ + r] = rp2;
      st[ST_V  + NXQ + r] = rp2 - 0.9;
      ws[OFF_Q2 + tid * M2Q + r] = rp2 + 0.1;
    }
  }
}

// ---------------------------------------------------------------------------
// sbuild core (R13 verbatim): 32x32 lower tile -> SG tile-major
// ---------------------------------------------------------------------------
__device__ __forceinline__ void sbuild_core(const float* __restrict__ G2,
                                            const double* __restrict__ ainv,
                                            double* __restrict__ arena,
                                            double* __restrict__ Sgb, const int tile) {
  const int tid = threadIdx.x, wave = tid >> 6, lane = tid & 63;
  const int R0 = TRI_R[tile] * 32, C0 = TRI_C[tile] * 32;
  double* As = arena + wave * 2176;
  double* Bs = As + 1088;
  const int k0w = wave * 183;
  const int kend = min(k0w + 183, NXQ);
  const int rg4 = (lane >> 3) * 4, cg4 = (lane & 7) * 4;
  double acc[4][4];
#pragma unroll
  for (int i = 0; i < 4; ++i)
#pragma unroll
    for (int j = 0; j < 4; ++j) acc[i][j] = 0.0;
  const int kk2 = lane & 31;
  for (int ch = 0; ch < 6; ++ch) {
    __syncthreads();
    if (wave < 4) {
      const int k = k0w + ch * 32 + kk2;
      const bool ok = (k < kend);
      const double aik = ok ? ainv[k] : 0.0;
#pragma unroll
      for (int it = 0; it < 16; ++it) {
        const int rr = (it << 1) | (lane >> 5);
        double av = 0.0, bv = 0.0;
        if (ok) {
          av = (double)G2[(R0 + rr) * NXQ + k] * aik;
          bv = (double)G2[(C0 + rr) * NXQ + k];
        }
        As[kk2 * 34 + rr] = av;
        Bs[kk2 * 34 + rr] = bv;
      }
    }
    __syncthreads();
    if (wave < 4) {
#pragma unroll 8
      for (int q = 0; q < 32; ++q) {
        const double a0 = As[q*34 + rg4 + 0], a1 = As[q*34 + rg4 + 1],
                     a2 = As[q*34 + rg4 + 2], a3 = As[q*34 + rg4 + 3];
        const double b0 = Bs[q*34 + cg4 + 0], b1 = Bs[q*34 + cg4 + 1],
                     b2 = Bs[q*34 + cg4 + 2], b3 = Bs[q*34 + cg4 + 3];
        acc[0][0] += a0*b0; acc[0][1] += a0*b1; acc[0][2] += a0*b2; acc[0][3] += a0*b3;
        acc[1][0] += a1*b0; acc[1][1] += a1*b1; acc[1][2] += a1*b2; acc[1][3] += a1*b3;
        acc[2][0] += a2*b0; acc[2][1] += a2*b1; acc[2][2] += a2*b2; acc[2][3] += a2*b3;
        acc[3][0] += a3*b0; acc[3][1] += a3*b1; acc[3][2] += a3*b2; acc[3][3] += a3*b3;
      }
    }
  }
  __syncthreads();
  if (wave < 4) {
#pragma unroll
    for (int i = 0; i < 4; ++i)
#pragma unroll
      for (int j = 0; j < 4; ++j)
        As[(rg4 + i) * 32 + cg4 + j] = acc[i][j];
  }
  __syncthreads();
  for (int idx = tid; idx < 1024; idx += 512) {
    const double v = arena[idx] + arena[2176 + idx] + arena[4352 + idx] + arena[6528 + idx];
    Sgb[tile * 1024 + idx] = v;
  }
}

// ---------------------------------------------------------------------------
// ps (pre-loop only): grid (12, 16) x 512 (R13 verbatim)
// ---------------------------------------------------------------------------
__global__ __launch_bounds__(512)
void ps_kernel(const float* __restrict__ G2, double* __restrict__ ws) {
  const int tile = blockIdx.x, b = blockIdx.y;
  const int tid = threadIdx.x, lane = tid & 63;
  extern __shared__ double sm[];
  double* st = ws + OFF_ST + b * STB;   // set 0
  {
    double* uvec = sm;
    double* part = sm + 128;
    double* yl   = sm + 640;
    const int c0 = tile * 64;
    if (tid < M2Q) uvec[tid] = ws[OFF_Q2 + b * M2Q + tid];
    __syncthreads();
    const int kk = tid & 63, rq = tid >> 6;
    const int k = c0 + kk;
    const int kg = (k < NXQ) ? k : (NXQ - 1);
    {
      const float* gp = G2 + (rq * 16) * NXQ + kg;
      double acc = 0.0;
#pragma unroll
      for (int j = 0; j < 16; ++j) acc = fma((double)gp[j * NXQ], uvec[rq * 16 + j], acc);
      part[rq * 64 + kk] = acc;
    }
    __syncthreads();
    if (tid < 64) {
      const int k2 = c0 + tid;
      double y = 0.0;
      if (k2 < NXQ) {
        double w = 0.0;
#pragma unroll
        for (int q = 0; q < 8; ++q) w += part[q * 64 + tid];
        const double rhsk = -(QPEN_ * st[ST_Z + k2] + ws[OFF_P + b * NXQ + k2]
                              - st[ST_LAM + k2] - st[ST_V + k2] + w);
        y = st[ST_AINV + k2] * rhsk;
        st[ST_Y + k2] = y;
      }
      yl[tid] = y;
    }
    __syncthreads();
    const double yv = yl[lane];
#pragma unroll
    for (int jr = 0; jr < 16; ++jr) {
      const int r = (tid >> 6) * 16 + jr;
      double v = (double)G2[r * NXQ + kg] * yv;
      v = wred_sum(v);
      if (lane == 0) ws[OFF_TP + (tile * BQ + b) * M2Q + r] = v;
    }
    __syncthreads();
  }
  if (tile < 10)
    sbuild_core(G2, st + ST_AINV, sm, ws + OFF_SG + b * 10240, tile);
}

// ---------------------------------------------------------------------------
// dps: grid (12, 16) x 512. Each block REDUNDANTLY factors K and solves for u
// (R12-verbatim solve body; S/TP from previous kernel -> coherent), then
// dz + alpha + own-slice state update + prep chunk + sbuild tile.
// ---------------------------------------------------------------------------
__global__ __launch_bounds__(512, 1)
void dps_kernel(const float* __restrict__ G2, double* __restrict__ ws,
                float* __restrict__ out, const int ph, const int last) {
  const int chunk = blockIdx.x, b = blockIdx.y;
  const int tid = threadIdx.x, wave = tid >> 6, lane = tid & 63;
  extern __shared__ double sm[];
  double (*Sl)[129] = (double(*)[129])(sm + L_SL);
  double* us   = sm + L_US;     // u — survives into dps phases
  double* invd = sm + L_INVD;   // invd during factor; g2b after
  double* red2 = sm + L_RED2;
  const double* R = ws + OFF_ST + ph * BQ * STB + b * STB;
  double*       W = ws + OFF_ST + (1 - ph) * BQ * STB + b * STB;
  double* Sgb  = ws + OFF_SG + b * 10240;
  const int c0 = chunk * 64;

  // ===== SOLVE PHASE (R12 verbatim, b-indexed, no global tail) =====
#pragma unroll
  for (int t = 0; t < 10; ++t) {
    const int R0 = TRI_R[t] * 32, C0 = TRI_C[t] * 32;
    const bool offd = (R0 != C0);
    for (int e = tid; e < 1024; e += 512) {
      const int r = e >> 5, c = e & 31;
      const double v = Sgb[t * 1024 + e];
      Sl[R0 + r][C0 + c] = v;
      if (offd) Sl[C0 + c][R0 + r] = v;
    }
  }
  if (tid < M2Q) {
    double t = 0.0;
#pragma unroll
    for (int c = 0; c < 12; ++c) t += ws[OFF_TP + (c * BQ + b) * M2Q + tid];
    us[tid] = t;
  }
  __syncthreads();
  if (tid < M2Q) Sl[tid][tid] += R[ST_S + NXQ + tid] / R[ST_LAM + NXQ + tid];
  __syncthreads();

  int rowm[4], colm[4];
  {
    const int rc = lane & 15, kq = lane >> 4;
    const double avr = (kq == 0) ? (double)rc : 0.0;
    const double bv1 = (kq == 0) ? 1.0 : 0.0;
    const double av1 = (kq == 0) ? 1.0 : 0.0;
    const double bvc = (kq == 0) ? (double)rc : 0.0;
    d4 zero = {0.0, 0.0, 0.0, 0.0};
    d4 dr = __builtin_amdgcn_mfma_f64_16x16x4f64(avr, bv1, zero, 0, 0, 0);
    d4 dc = __builtin_amdgcn_mfma_f64_16x16x4f64(av1, bvc, zero, 0, 0, 0);
#pragma unroll
    for (int e = 0; e < 4; ++e) { rowm[e] = (int)dr[e]; colm[e] = (int)dc[e]; }
  }

  for (int kb = 0; kb < 8; ++kb) {
    const int K0 = kb * 16, J0 = K0 + 16, T = 128 - J0;
    if (wave == 0 && lane < 16) {
      const int r = lane;
      double a[16];
#pragma unroll
      for (int c = 0; c < 16; ++c) a[c] = Sl[K0 + r][K0 + c];
#pragma unroll
      for (int c = 0; c < 16; ++c) {
        const double dcc = __shfl(a[c], c, 64);
        const double rs = rsqrt64(dcc);
        a[c] *= rs;
        if (lane == c) invd[K0 + c] = rs;
#pragma unroll
        for (int k2 = c + 1; k2 < 16; ++k2) {
          const double lkc = __shfl(a[c], k2, 64);
          a[k2] = fma(-a[c], lkc, a[k2]);
        }
      }
#pragma unroll
      for (int c = 0; c < 16; ++c) Sl[K0 + r][K0 + c] = a[c];
    }
    __syncthreads();

    if (tid <= T) {
      const bool isU = (tid == T);
      double l[16];
      if (isU) {
#pragma unroll
        for (int c = 0; c < 16; ++c) l[c] = us[K0 + c];
      } else {
#pragma unroll
        for (int c = 0; c < 16; ++c) l[c] = Sl[J0 + tid][K0 + c];
      }
#pragma unroll
      for (int c = 0; c < 16; ++c) {
        const double lc = l[c] * invd[K0 + c];
        l[c] = lc;
#pragma unroll
        for (int k2 = c + 1; k2 < 16; ++k2)
          l[k2] = fma(-lc, Sl[K0 + k2][K0 + c], l[k2]);
      }
      if (isU) {
#pragma unroll
        for (int c = 0; c < 16; ++c) us[K0 + c] = l[c];
      } else {
#pragma unroll
        for (int c = 0; c < 16; ++c) Sl[J0 + tid][K0 + c] = l[c];
      }
    }
    __syncthreads();

    if (kb < 7) {
      if (tid < T) {
        double acc = 0.0;
#pragma unroll
        for (int c = 0; c < 16; ++c) acc = fma(Sl[J0 + tid][K0 + c], us[K0 + c], acc);
        us[J0 + tid] -= acc;
      }
      const int Tb = 7 - kb;
      const int rc = lane & 15, kq = lane >> 4;
      for (int idx = wave; idx < Tb * Tb; idx += 8) {
        const int i0 = J0 + (idx / Tb) * 16;
        const int j0 = J0 + (idx % Tb) * 16;
        d4 acc;
#pragma unroll
        for (int e = 0; e < 4; ++e) acc[e] = Sl[i0 + rowm[e]][j0 + colm[e]];
#pragma unroll
        for (int m = 0; m < 4; ++m) {
          const double av = -Sl[i0 + rc][K0 + 4 * m + kq];
          const double bv =  Sl[j0 + rc][K0 + 4 * m + kq];
          acc = __builtin_amdgcn_mfma_f64_16x16x4f64(av, bv, acc, 0, 0, 0);
        }
#pragma unroll
        for (int e = 0; e < 4; ++e) Sl[i0 + rowm[e]][j0 + colm[e]] = acc[e];
      }
    }
    __syncthreads();
  }

  for (int kb = 7; kb >= 0; --kb) {
    const int K0 = kb * 16;
    if (kb < 7) {
      const int c = tid & 15, ch = tid >> 4;
      double part = 0.0;
      for (int k = K0 + 16 + ch; k < 128; k += 32) part = fma(Sl[k][K0 + c], us[k], part);
      red2[c * 32 + ch] = part;
      __syncthreads();
      if (tid < 16) {
        double acc = 0.0;
#pragma unroll
        for (int q = 0; q < 32; ++q) acc += red2[tid * 32 + q];
        us[K0 + tid] -= acc;
      }
      __syncthreads();
    }
    if (wave == 0 && lane < 16) {
      const int j = lane;
      double colv[16];
#pragma unroll
      for (int c = 0; c < 16; ++c) colv[c] = Sl[K0 + c][K0 + j];
      double x = us[K0 + j];
      const double iv = invd[K0 + j];
#pragma unroll
      for (int cc = 0; cc < 16; ++cc) {
        const int c = 15 - cc;
        const double xiv = x * iv;
        const double uc = __shfl(xiv, c, 64);
        if (j == c) x = xiv;
        else if (j < c) x = fma(-colv[c], uc, x);
      }
      us[K0 + j] = x;
    }
    __syncthreads();
  }
  // g2b = D2inv * u (into invd's dead slot)
  if (tid < M2Q) invd[tid] = (R[ST_S + NXQ + tid] / R[ST_LAM + NXQ + tid]) * us[tid];
  __syncthreads();
  double* g2b = invd;

  // ===== DPS PHASES (aliased into dead Sl region) =====
  double* dzl   = sm + D_DZ;
  double* red   = sm + D_RED;
  double* sc    = sm + D_SC;
  double* ainvn = sm + D_AINV;
  double* q2l   = sm + D_Q2;
  double* yl    = sm + D_YL;
  double* snew  = sm + D_SN;
  double* lnew  = sm + D_LN;
  double* part  = sm + D_PART;

  // dz (coalesced column-parallel matvec; u read from LDS)
  for (int k = tid; k < NXQ; k += 512) {
    double acc = 0.0;
    const float* gp = G2 + k;
#pragma unroll 8
    for (int r = 0; r < M2Q; ++r) acc = fma((double)gp[r * NXQ], us[r], acc);
    dzl[k] = R[ST_Y + k] - R[ST_AINV + k] * acc;
  }
  __syncthreads();

  // alpha (full, redundant, deterministic)
  double lmin = 1e300;
  for (int i = tid; i < MQ; i += 512) {
    const double si = R[ST_S + i], li = R[ST_LAM + i], di = li / si;
    double dsi, dlami;
    if (i < NXQ) {
      const double dz = dzl[i];
      dsi = dz - R[ST_RP + i];
      dlami = R[ST_V + i] - di * dz;
    } else {
      const double g = g2b[i - NXQ];
      dsi = -R[ST_RP + i] - g;
      dlami = R[ST_V + i] + di * g;
    }
    if (dsi < 0.0)   lmin = fmin(lmin, -si / dsi);
    if (dlami < 0.0) lmin = fmin(lmin, -li / dlami);
  }
  lmin = wred_min(lmin);
  if (lane == 0) red[wave] = lmin;
  __syncthreads();
  if (tid == 0) {
    double m = red[0];
#pragma unroll
    for (int w = 1; w < 8; ++w) m = fmin(m, red[w]);
    sc[0] = fmin(1.0, 0.99 * m);
  }
  __syncthreads();
  const double alpha = sc[0];

  if (last) {
    const int k2 = c0 + (tid & 63);
    if (tid < 64 && k2 < NXQ)
      out[b * NXQ + k2] = (float)(R[ST_Z + k2] + alpha * dzl[k2]);
    return;
  }

  // s/lam update + musum (fixed order -> identical across blocks)
  double musum = 0.0;
  for (int i = tid; i < MQ; i += 512) {
    const double si = R[ST_S + i], li = R[ST_LAM + i], di = li / si;
    double dsi, dlami;
    if (i < NXQ) {
      const double dz = dzl[i];
      dsi = dz - R[ST_RP + i];
      dlami = R[ST_V + i] - di * dz;
    } else {
      const double g = g2b[i - NXQ];
      dsi = -R[ST_RP + i] - g;
      dlami = R[ST_V + i] + di * g;
    }
    const double sn = si + alpha * dsi, ln = li + alpha * dlami;
    snew[i] = sn; lnew[i] = ln;
    musum += sn * ln;
  }
  musum = wred_sum(musum);
  if (lane == 0) red[wave] = musum;
  __syncthreads();
  if (tid == 0) {
    double t = 0.0;
#pragma unroll
    for (int w = 0; w < 8; ++w) t += red[w];
    sc[1] = SIGMA_ * (t / (double)MQ);
  }
  __syncthreads();
  const double smu = sc[1];

  // derived state; own-slice writes to W
  for (int i = tid; i < MQ; i += 512) {
    const double sn = snew[i], ln = lnew[i], di = ln / sn;
    if (i < NXQ) {
      const double zn = R[ST_Z + i] + alpha * dzl[i];
      const double rpn = sn - zn;
      const double vn = smu / sn - ln + di * rpn;
      const double an = 1.0 / (QPEN_ + di);
      ainvn[i] = an;
      if ((i >> 6) == chunk) {
        W[ST_Z + i] = zn; W[ST_S + i] = sn; W[ST_LAM + i] = ln;
        W[ST_RP + i] = rpn; W[ST_V + i] = vn; W[ST_AINV + i] = an;
      }
    } else {
      const int m = i - NXQ;
      const double gzn = R[ST_GZ + m] + alpha * g2b[m];
      const double rpn = gzn + sn - ws[OFF_H2 + m];
      const double vn = smu / sn - ln + di * rpn;
      q2l[m] = ln + vn;
      if (chunk == 0) {
        W[ST_S + i] = sn; W[ST_LAM + i] = ln;
        W[ST_RP + i] = rpn; W[ST_V + i] = vn; W[ST_GZ + m] = gzn;
      }
    }
  }
  __syncthreads();

  // prep chunk (rhs, y, t partials) from LDS-local new state
  {
    const int kk = tid & 63, rq = tid >> 6;
    const int k = c0 + kk;
    const int kg = (k < NXQ) ? k : (NXQ - 1);
    {
      const float* gp = G2 + (rq * 16) * NXQ + kg;
      double acc = 0.0;
#pragma unroll
      for (int j = 0; j < 16; ++j) acc = fma((double)gp[j * NXQ], q2l[rq * 16 + j], acc);
      part[rq * 64 + kk] = acc;
    }
    __syncthreads();
    if (tid < 64) {
      const int k2 = c0 + tid;
      double y = 0.0;
      if (k2 < NXQ) {
        double w = 0.0;
#pragma unroll
        for (int q = 0; q < 8; ++q) w += part[q * 64 + tid];
        const double sn = snew[k2], ln = lnew[k2], di = ln / sn;
        const double zn = R[ST_Z + k2] + alpha * dzl[k2];
        const double rpn = sn - zn;
        const double vn = smu / sn - ln + di * rpn;
        const double rhsk = -(QPEN_ * zn + ws[OFF_P + b * NXQ + k2] - ln - vn + w);
        y = ainvn[k2] * rhsk;
        W[ST_Y + k2] = y;
      }
      yl[tid] = y;
    }
    __syncthreads();
    const double yv = yl[lane];
#pragma unroll
    for (int jr = 0; jr < 16; ++jr) {
      const int r = (tid >> 6) * 16 + jr;
      double v = (double)G2[r * NXQ + kg] * yv;
      v = wred_sum(v);
      if (lane == 0) ws[OFF_TP + (chunk * BQ + b) * M2Q + r] = v;
    }
    __syncthreads();
  }

  // sbuild tile (blocks 0..9) with LDS ainvn
  if (chunk < 10)
    sbuild_core(G2, ainvn, sm + D_AR, Sgb, chunk);
}

extern "C" void kernel_launch(void* const* d_in, const int* in_sizes, int n_in,
                              void* d_out, int out_size, void* d_ws, size_t ws_size,
                              hipStream_t stream) {
  const float* puzzles = (const float*)d_in[0];
  const float* G2      = (const float*)d_in[1];
  const float* z2      = (const float*)d_in[2];
  const float* s2      = (const float*)d_in[3];
  float* out = (float*)d_out;
  double* ws = (double*)d_ws;

  (void)hipFuncSetAttribute(reinterpret_cast<const void*>(&dps_kernel),
                            hipFuncAttributeMaxDynamicSharedMemorySize, SH_FUSED);
  (void)hipFuncSetAttribute(reinterpret_cast<const void*>(&ps_kernel),
                            hipFuncAttributeMaxDynamicSharedMemorySize, SH_PS);

  init_kernel<<<dim3(16 + M2Q), dim3(512), 0, stream>>>(puzzles, G2, z2, s2, ws);
  ps_kernel<<<dim3(12, BQ), dim3(512), SH_PS, stream>>>(G2, ws);
  for (int it = 0; it < 10; ++it) {
    const int ph = it & 1;
    dps_kernel<<<dim3(12, BQ), dim3(512), SH_FUSED, stream>>>(G2, ws, out, ph, (it == 9) ? 1 : 0);
  }
}